// Round 2
// baseline (4933.022 us; speedup 1.0000x reference)
//
#include <hip/hip_runtime.h>
#include <hip/hip_bf16.h>

#define S_LEN 2048
#define DMODEL 768
#define NHEAD 12
#define DKH 64
#define DFF_K 3072
#define MROWS 4096   // B*S

__device__ __forceinline__ float bfu2f(unsigned short u) {
  return __uint_as_float(((unsigned int)u) << 16);
}
__device__ __forceinline__ unsigned short f2bfu(float f) {
  __hip_bfloat16 h = __float2bfloat16(f);
  return *reinterpret_cast<unsigned short*>(&h);
}

// ---------------------------------------------------------------------------
// Tiled GEMM: C[M x N] = act(A[M x K] @ B[K x N] + bias[N]); fp32 math.
// A may be bf16 (a_bf16), C may be written bf16 (c_bf16). BM=BN=64, BK=16,
// 256 threads, 4x4 register tile. head_blocked: B is [H][K][64] stacked.
// ---------------------------------------------------------------------------
__global__ __launch_bounds__(256) void gemm_kernel(
    const void* __restrict__ Av,
    const float* __restrict__ B,
    const float* __restrict__ bias,
    void* __restrict__ Cv,
    int K, int lda, int ldb, int ldc,
    int head_blocked, int relu, int a_bf16, int c_bf16)
{
  __shared__ float Xs[16][64];   // [k][row]  (transposed A tile)
  __shared__ float Ws[16][64];   // [k][col]
  const int tid  = threadIdx.x;
  const int row0 = blockIdx.y * 64;
  const int col0 = blockIdx.x * 64;

  const float* Bblk;
  int ldbB, bc_base;
  if (head_blocked) {
    Bblk = B + (size_t)(col0 >> 6) * (size_t)K * 64;  // head offset
    ldbB = 64; bc_base = 0;
  } else {
    Bblk = B; ldbB = ldb; bc_base = col0;
  }

  const int tx  = tid & 15;        // col group
  const int ty  = tid >> 4;        // row group
  const int ar  = tid >> 2;        // A stage: row 0..63
  const int ak0 = (tid & 3) << 2;  // A stage: k offset 0,4,8,12
  const int bk  = tid >> 4;        // B stage: k 0..15
  const int bc0 = (tid & 15) << 2; // B stage: col offset

  float acc[4][4] = {{0.f,0.f,0.f,0.f},{0.f,0.f,0.f,0.f},
                     {0.f,0.f,0.f,0.f},{0.f,0.f,0.f,0.f}};

  for (int kb = 0; kb < K; kb += 16) {
    const size_t aidx = (size_t)(row0 + ar) * lda + kb + ak0;
    float4 af;
    if (a_bf16) {
      ushort4 a4 = *(const ushort4*)((const unsigned short*)Av + aidx);
      af = make_float4(bfu2f(a4.x), bfu2f(a4.y), bfu2f(a4.z), bfu2f(a4.w));
    } else {
      af = *(const float4*)((const float*)Av + aidx);
    }
    float4 b4 = *(const float4*)(Bblk + (size_t)(kb + bk) * ldbB + bc_base + bc0);
    Xs[ak0 + 0][ar] = af.x;
    Xs[ak0 + 1][ar] = af.y;
    Xs[ak0 + 2][ar] = af.z;
    Xs[ak0 + 3][ar] = af.w;
    *(float4*)&Ws[bk][bc0] = b4;
    __syncthreads();
#pragma unroll
    for (int dd = 0; dd < 16; ++dd) {
      float4 av = *(const float4*)&Xs[dd][ty << 2];  // broadcast across 16 lanes
      float4 bv = *(const float4*)&Ws[dd][tx << 2];  // 2-way aliasing (free)
      float aa[4] = {av.x, av.y, av.z, av.w};
      float bb[4] = {bv.x, bv.y, bv.z, bv.w};
#pragma unroll
      for (int i = 0; i < 4; ++i)
#pragma unroll
        for (int j = 0; j < 4; ++j)
          acc[i][j] += aa[i] * bb[j];
    }
    __syncthreads();
  }

  float bvv[4];
#pragma unroll
  for (int j = 0; j < 4; ++j) bvv[j] = bias[col0 + (tx << 2) + j];

#pragma unroll
  for (int i = 0; i < 4; ++i) {
    const int r = row0 + (ty << 2) + i;
    const size_t cidx = (size_t)r * ldc + col0 + (tx << 2);
    float v[4];
#pragma unroll
    for (int j = 0; j < 4; ++j) {
      v[j] = acc[i][j] + bvv[j];
      if (relu) v[j] = fmaxf(v[j], 0.f);
    }
    if (c_bf16) {
      ushort4 o;
      o.x = f2bfu(v[0]); o.y = f2bfu(v[1]); o.z = f2bfu(v[2]); o.w = f2bfu(v[3]);
      *(ushort4*)((unsigned short*)Cv + cidx) = o;
    } else {
      *(float4*)((float*)Cv + cidx) = make_float4(v[0], v[1], v[2], v[3]);
    }
  }
}

// ---------------------------------------------------------------------------
// Attention: Q,K,V fp32 in [B,S,H,DK] layout ([4096 x 768], head-blocked
// cols). One block = 4 waves = 4 query rows of one (b,h). Each wave is fully
// private (own score row in LDS, shuffle reductions) -> no barriers.
// ---------------------------------------------------------------------------
__global__ __launch_bounds__(256) void attn_kernel(
    const float* __restrict__ Q,
    const float* __restrict__ K,
    const float* __restrict__ V,
    float* __restrict__ O)
{
  __shared__ float sc[4][S_LEN];   // 32 KB score rows
  __shared__ float qs[4][DKH];
  const int tid  = threadIdx.x;
  const int lane = tid & 63;
  const int wv   = tid >> 6;       // wave id = local q row
  const int b    = blockIdx.z, h = blockIdx.y;
  const int q0   = blockIdx.x * 4;
  const size_t base = (size_t)b * S_LEN * DMODEL + (size_t)h * DKH;

  // load own q row (wave wv loads qs[wv])
  qs[wv][lane] = Q[base + (size_t)(q0 + wv) * DMODEL + lane];

  // scores: wave wv computes sc[wv][0..2047]
  {
    const float* q = qs[wv];
    for (int t = lane; t < S_LEN; t += 64) {
      const float* kp = K + base + (size_t)t * DMODEL;
      float s = 0.f;
#pragma unroll
      for (int d = 0; d < DKH; d += 4) {
        float4 kv = *(const float4*)(kp + d);
        s += q[d] * kv.x + q[d + 1] * kv.y + q[d + 2] * kv.z + q[d + 3] * kv.w;
      }
      sc[wv][t] = s * 0.125f;  // 1/sqrt(64)
    }
  }

  // softmax over own row (shuffle butterflies leave result in all lanes)
  float inv;
  {
    float m = -1e30f;
    for (int t = lane; t < S_LEN; t += 64) m = fmaxf(m, sc[wv][t]);
#pragma unroll
    for (int o = 32; o; o >>= 1) m = fmaxf(m, __shfl_xor(m, o));
    float sum = 0.f;
    for (int t = lane; t < S_LEN; t += 64) {
      float e = __expf(sc[wv][t] - m);
      sc[wv][t] = e;
      sum += e;
    }
#pragma unroll
    for (int o = 32; o; o >>= 1) sum += __shfl_xor(sum, o);
    inv = 1.f / sum;
  }

  // PV: lane d accumulates ctx[q0+wv][d]; V rows coalesced 256B/wave
  {
    const int d = lane;
    const float* vp = V + base + d;
    const float* p = sc[wv];
    float a0 = 0.f, a1 = 0.f, a2 = 0.f, a3 = 0.f;
    for (int t = 0; t < S_LEN; t += 4) {
      a0 += p[t]     * vp[(size_t)(t)     * DMODEL];
      a1 += p[t + 1] * vp[(size_t)(t + 1) * DMODEL];
      a2 += p[t + 2] * vp[(size_t)(t + 2) * DMODEL];
      a3 += p[t + 3] * vp[(size_t)(t + 3) * DMODEL];
    }
    float acc = ((a0 + a1) + (a2 + a3)) * inv;
    O[base + (size_t)(q0 + wv) * DMODEL + d] = acc;
  }
}

// ---------------------------------------------------------------------------
// out = LayerNorm(X + Y) * w + b   (row = 768, block = 256 threads)
// ---------------------------------------------------------------------------
__global__ __launch_bounds__(256) void add_ln_kernel(
    const float* __restrict__ X,
    const float* __restrict__ Y,
    const float* __restrict__ w,
    const float* __restrict__ bvec,
    float* __restrict__ out)
{
  __shared__ float buf[DMODEL];
  __shared__ float rbuf[8];
  const int tid  = threadIdx.x;
  const int lane = tid & 63, wv = tid >> 6;
  const size_t base = (size_t)blockIdx.x * DMODEL;

  float s = 0.f, s2 = 0.f;
#pragma unroll
  for (int j = tid; j < DMODEL; j += 256) {
    float v = X[base + j] + Y[base + j];
    buf[j] = v; s += v; s2 += v * v;
  }
#pragma unroll
  for (int o = 32; o; o >>= 1) { s += __shfl_xor(s, o); s2 += __shfl_xor(s2, o); }
  if (lane == 0) { rbuf[wv] = s; rbuf[4 + wv] = s2; }
  __syncthreads();
  const float S  = rbuf[0] + rbuf[1] + rbuf[2] + rbuf[3];
  const float S2 = rbuf[4] + rbuf[5] + rbuf[6] + rbuf[7];
  const float mean = S * (1.f / (float)DMODEL);
  const float var  = S2 * (1.f / (float)DMODEL) - mean * mean;
  const float rstd = rsqrtf(var + 1e-5f);
#pragma unroll
  for (int j = tid; j < DMODEL; j += 256) {
    float v = (buf[j] - mean) * rstd * w[j] + bvec[j];
    out[base + j] = v;
  }
}

// ---------------------------------------------------------------------------
extern "C" void kernel_launch(void* const* d_in, const int* in_sizes, int n_in,
                              void* d_out, int out_size, void* d_ws, size_t ws_size,
                              hipStream_t stream) {
  const float* src  = (const float*)d_in[0];
  const float* Wq   = (const float*)d_in[1];
  const float* bq   = (const float*)d_in[2];
  const float* Wk   = (const float*)d_in[3];
  const float* bk   = (const float*)d_in[4];
  const float* Wv   = (const float*)d_in[5];
  const float* bv   = (const float*)d_in[6];
  const float* Wo   = (const float*)d_in[7];
  const float* bo   = (const float*)d_in[8];
  const float* ln1w = (const float*)d_in[9];
  const float* ln1b = (const float*)d_in[10];
  const float* W1   = (const float*)d_in[11];
  const float* b1   = (const float*)d_in[12];
  const float* W2   = (const float*)d_in[13];
  const float* b2   = (const float*)d_in[14];
  const float* ln2w = (const float*)d_in[15];
  const float* ln2b = (const float*)d_in[16];

  // workspace layout, with aliasing:
  //   qb kb vb ctx : 4 x [4096*768] fp32          (50.3 MB)
  //   ff           : [4096*3072] bf16 (ushort)    (25.2 MB)
  //   ao := qb, x1 := kb, y2 := vb  (dead after attention)
  float* ws = (float*)d_ws;
  const size_t SEG = (size_t)MROWS * DMODEL;  // 3.146M elems
  float* qb  = ws;
  float* kb_ = ws + SEG;
  float* vb_ = ws + 2 * SEG;
  float* ctx = ws + 3 * SEG;
  unsigned short* ff = (unsigned short*)(ws + 4 * SEG);  // 4096*3072 bf16
  float* ao  = qb;
  float* x1  = kb_;
  float* y2  = vb_;
  (void)ws_size; (void)in_sizes; (void)n_in; (void)out_size;

  dim3 blk(256);
  dim3 gQKV(DMODEL / 64, MROWS / 64);   // 12 x 64

  // 1-3: QKV projections (head-blocked weights), out layout [B,S,H,DK]
  gemm_kernel<<<gQKV, blk, 0, stream>>>(src, Wq, bq, qb,  DMODEL, DMODEL, 64, DMODEL, 1, 0, 0, 0);
  gemm_kernel<<<gQKV, blk, 0, stream>>>(src, Wk, bk, kb_, DMODEL, DMODEL, 64, DMODEL, 1, 0, 0, 0);
  gemm_kernel<<<gQKV, blk, 0, stream>>>(src, Wv, bv, vb_, DMODEL, DMODEL, 64, DMODEL, 1, 0, 0, 0);

  // 4: attention -> ctx [B,S,H*DK]
  dim3 ga(S_LEN / 4, NHEAD, 2);
  attn_kernel<<<ga, blk, 0, stream>>>(qb, kb_, vb_, ctx);

  // 5: attn_out = ctx @ Wo + bo
  gemm_kernel<<<gQKV, blk, 0, stream>>>(ctx, Wo, bo, ao, DMODEL, DMODEL, DMODEL, DMODEL, 0, 0, 0, 0);

  // 6: x1 = LN(src + attn_out)
  add_ln_kernel<<<dim3(MROWS), blk, 0, stream>>>(src, ao, ln1w, ln1b, x1);

  // 7: ff = relu(x1 @ W1 + b1), stored bf16
  dim3 gF1(DFF_K / 64, MROWS / 64);     // 48 x 64
  gemm_kernel<<<gF1, blk, 0, stream>>>(x1, W1, b1, ff, DMODEL, DMODEL, DFF_K, DFF_K, 0, 1, 0, 1);

  // 8: y2 = ff @ W2 + b2  (A is bf16)
  gemm_kernel<<<gQKV, blk, 0, stream>>>(ff, W2, b2, y2, DFF_K, DFF_K, DMODEL, DMODEL, 0, 0, 1, 0);

  // 9: out = LN(x1 + y2)
  add_ln_kernel<<<dim3(MROWS), blk, 0, stream>>>(x1, y2, ln2w, ln2b, (float*)d_out);
}

// Round 3
// 1451.907 us; speedup vs baseline: 3.3976x; 3.3976x over previous
//
#include <hip/hip_runtime.h>
#include <hip/hip_bf16.h>

#define S_LEN 2048
#define DMODEL 768
#define NHEAD 12
#define DKH 64
#define DFF_K 3072
#define MROWS 4096   // B*S

__device__ __forceinline__ float bfu2f(unsigned short u) {
  return __uint_as_float(((unsigned int)u) << 16);
}
__device__ __forceinline__ unsigned short f2bfu(float f) {
  __hip_bfloat16 h = __float2bfloat16(f);
  return *reinterpret_cast<unsigned short*>(&h);
}

// ---------------------------------------------------------------------------
// Tiled GEMM: C[M x N] = act(A[M x K] @ B[K x N] + bias[N]); fp32 math.
// A may be bf16 (a_bf16), C may be written bf16 (c_bf16). BM=BN=64, BK=16,
// 256 threads, 4x4 register tile. head_blocked: B is [H][K][64] stacked.
// ---------------------------------------------------------------------------
__global__ __launch_bounds__(256) void gemm_kernel(
    const void* __restrict__ Av,
    const float* __restrict__ B,
    const float* __restrict__ bias,
    void* __restrict__ Cv,
    int K, int lda, int ldb, int ldc,
    int head_blocked, int relu, int a_bf16, int c_bf16)
{
  __shared__ float Xs[16][64];   // [k][row]  (transposed A tile)
  __shared__ float Ws[16][64];   // [k][col]
  const int tid  = threadIdx.x;
  const int row0 = blockIdx.y * 64;
  const int col0 = blockIdx.x * 64;

  const float* Bblk;
  int ldbB, bc_base;
  if (head_blocked) {
    Bblk = B + (size_t)(col0 >> 6) * (size_t)K * 64;  // head offset
    ldbB = 64; bc_base = 0;
  } else {
    Bblk = B; ldbB = ldb; bc_base = col0;
  }

  const int tx  = tid & 15;        // col group
  const int ty  = tid >> 4;        // row group
  const int ar  = tid >> 2;        // A stage: row 0..63
  const int ak0 = (tid & 3) << 2;  // A stage: k offset 0,4,8,12
  const int bk  = tid >> 4;        // B stage: k 0..15
  const int bc0 = (tid & 15) << 2; // B stage: col offset

  float acc[4][4] = {{0.f,0.f,0.f,0.f},{0.f,0.f,0.f,0.f},
                     {0.f,0.f,0.f,0.f},{0.f,0.f,0.f,0.f}};

  for (int kb = 0; kb < K; kb += 16) {
    const size_t aidx = (size_t)(row0 + ar) * lda + kb + ak0;
    float4 af;
    if (a_bf16) {
      ushort4 a4 = *(const ushort4*)((const unsigned short*)Av + aidx);
      af = make_float4(bfu2f(a4.x), bfu2f(a4.y), bfu2f(a4.z), bfu2f(a4.w));
    } else {
      af = *(const float4*)((const float*)Av + aidx);
    }
    float4 b4 = *(const float4*)(Bblk + (size_t)(kb + bk) * ldbB + bc_base + bc0);
    Xs[ak0 + 0][ar] = af.x;
    Xs[ak0 + 1][ar] = af.y;
    Xs[ak0 + 2][ar] = af.z;
    Xs[ak0 + 3][ar] = af.w;
    *(float4*)&Ws[bk][bc0] = b4;
    __syncthreads();
#pragma unroll
    for (int dd = 0; dd < 16; ++dd) {
      float4 av = *(const float4*)&Xs[dd][ty << 2];  // broadcast across 16 lanes
      float4 bv = *(const float4*)&Ws[dd][tx << 2];  // 2-way aliasing (free)
      float aa[4] = {av.x, av.y, av.z, av.w};
      float bb[4] = {bv.x, bv.y, bv.z, bv.w};
#pragma unroll
      for (int i = 0; i < 4; ++i)
#pragma unroll
        for (int j = 0; j < 4; ++j)
          acc[i][j] += aa[i] * bb[j];
    }
    __syncthreads();
  }

  float bvv[4];
#pragma unroll
  for (int j = 0; j < 4; ++j) bvv[j] = bias[col0 + (tx << 2) + j];

#pragma unroll
  for (int i = 0; i < 4; ++i) {
    const int r = row0 + (ty << 2) + i;
    const size_t cidx = (size_t)r * ldc + col0 + (tx << 2);
    float v[4];
#pragma unroll
    for (int j = 0; j < 4; ++j) {
      v[j] = acc[i][j] + bvv[j];
      if (relu) v[j] = fmaxf(v[j], 0.f);
    }
    if (c_bf16) {
      ushort4 o;
      o.x = f2bfu(v[0]); o.y = f2bfu(v[1]); o.z = f2bfu(v[2]); o.w = f2bfu(v[3]);
      *(ushort4*)((unsigned short*)Cv + cidx) = o;
    } else {
      *(float4*)((float*)Cv + cidx) = make_float4(v[0], v[1], v[2], v[3]);
    }
  }
}

// ---------------------------------------------------------------------------
// Flash-style attention. Block = 64 q-rows of one (b,h); 256 threads as a
// 16x16 grid, each owning a 4x4 tile. K/V staged in LDS per 64-row tile;
// online softmax with per-row (m,l) replicated across the row's 16 threads.
// P round-trips through LDS aliased over the dead K tile.
// LDS: Qs 17408 + KsPs 17408 + Vs 16384 = 51200 B -> 3 blocks/CU.
// Layouts: Qs[d][row] (stride 68, 16B-aligned float4), KsPs as Ks[d][t] /
// Ps[row][t] (stride 68), Vs[t][d] (stride 64).
// ---------------------------------------------------------------------------
#define AT_STR 68
__global__ __launch_bounds__(256) void flash_attn_kernel(
    const float* __restrict__ Q,
    const float* __restrict__ K,
    const float* __restrict__ V,
    float* __restrict__ O)
{
  __shared__ float Qs[64][AT_STR];
  __shared__ float KsPs[64][AT_STR];
  __shared__ float Vs[64][64];

  const int tid = threadIdx.x;
  const int tx  = tid & 15;       // col group (t-cols in S, d-cols in O)
  const int ty  = tid >> 4;       // row group (q rows)
  const int b   = blockIdx.z, h = blockIdx.y;
  const int q0  = blockIdx.x * 64;
  const size_t base = (size_t)b * S_LEN * DMODEL + (size_t)h * DKH;

  // staging map: 4 rounds of 16 rows; thread -> (row r*16+(tid>>4), d (tid&15)*4)
  const int st_r = tid >> 4;         // 0..15
  const int st_d = (tid & 15) << 2;  // 0,4,...,60

  // ---- stage Q tile (transposed into Qs[d][row]) ----
#pragma unroll
  for (int r = 0; r < 4; ++r) {
    const int row = r * 16 + st_r;
    float4 qv = *(const float4*)(Q + base + (size_t)(q0 + row) * DMODEL + st_d);
    Qs[st_d + 0][row] = qv.x;
    Qs[st_d + 1][row] = qv.y;
    Qs[st_d + 2][row] = qv.z;
    Qs[st_d + 3][row] = qv.w;
  }

  float m_run[4] = {-1e30f, -1e30f, -1e30f, -1e30f};
  float l_run[4] = {0.f, 0.f, 0.f, 0.f};
  float oacc[4][4] = {{0.f,0.f,0.f,0.f},{0.f,0.f,0.f,0.f},
                      {0.f,0.f,0.f,0.f},{0.f,0.f,0.f,0.f}};

  for (int kt = 0; kt < S_LEN; kt += 64) {
    __syncthreads();  // prev iter's Ps/Vs readers done; Q staged (iter 0)

    // ---- stage K (transposed -> Ks[d][t]) and V (natural -> Vs[t][d]) ----
#pragma unroll
    for (int r = 0; r < 4; ++r) {
      const int t = r * 16 + st_r;
      const size_t g = base + (size_t)(kt + t) * DMODEL + st_d;
      float4 kv = *(const float4*)(K + g);
      float4 vv = *(const float4*)(V + g);
      KsPs[st_d + 0][t] = kv.x;
      KsPs[st_d + 1][t] = kv.y;
      KsPs[st_d + 2][t] = kv.z;
      KsPs[st_d + 3][t] = kv.w;
      *(float4*)&Vs[t][st_d] = vv;
    }
    __syncthreads();

    // ---- S tile: s[i][j] = sum_d Qs[d][4ty+i] * Ks[d][4tx+j], * 1/8 ----
    float s[4][4] = {{0.f,0.f,0.f,0.f},{0.f,0.f,0.f,0.f},
                     {0.f,0.f,0.f,0.f},{0.f,0.f,0.f,0.f}};
#pragma unroll
    for (int dd = 0; dd < 64; ++dd) {
      float4 qv = *(const float4*)&Qs[dd][ty << 2];    // broadcast
      float4 kv = *(const float4*)&KsPs[dd][tx << 2];  // 2-way (free)
      float qq[4] = {qv.x, qv.y, qv.z, qv.w};
      float kk[4] = {kv.x, kv.y, kv.z, kv.w};
#pragma unroll
      for (int i = 0; i < 4; ++i)
#pragma unroll
        for (int j = 0; j < 4; ++j)
          s[i][j] += qq[i] * kk[j];
    }

    // ---- online softmax update (per row; state replicated over tx) ----
    float p[4][4];
    float alpha[4];
#pragma unroll
    for (int i = 0; i < 4; ++i) {
      float mt = fmaxf(fmaxf(s[i][0], s[i][1]), fmaxf(s[i][2], s[i][3])) * 0.125f;
#pragma unroll
      for (int o = 8; o; o >>= 1) mt = fmaxf(mt, __shfl_xor(mt, o));
      const float m_new = fmaxf(m_run[i], mt);
      alpha[i] = __expf(m_run[i] - m_new);
      float rs = 0.f;
#pragma unroll
      for (int j = 0; j < 4; ++j) {
        p[i][j] = __expf(s[i][j] * 0.125f - m_new);
        rs += p[i][j];
      }
#pragma unroll
      for (int o = 8; o; o >>= 1) rs += __shfl_xor(rs, o);
      l_run[i] = l_run[i] * alpha[i] + rs;
      m_run[i] = m_new;
#pragma unroll
      for (int j = 0; j < 4; ++j) oacc[i][j] *= alpha[i];
    }

    __syncthreads();  // all Ks reads done -> safe to overwrite with Ps

    // ---- write P (Ps[row][t], float4 along t) ----
#pragma unroll
    for (int i = 0; i < 4; ++i)
      *(float4*)&KsPs[(ty << 2) + i][tx << 2] =
          make_float4(p[i][0], p[i][1], p[i][2], p[i][3]);
    __syncthreads();

    // ---- PV: oacc[i][j] += sum_t Ps[4ty+i][t] * Vs[t][4tx+j] ----
#pragma unroll
    for (int t = 0; t < 64; ++t) {
      float4 vv = *(const float4*)&Vs[t][tx << 2];  // 2-way (free)
      float pv[4];
#pragma unroll
      for (int i = 0; i < 4; ++i) pv[i] = KsPs[(ty << 2) + i][t];  // broadcast
#pragma unroll
      for (int i = 0; i < 4; ++i) {
        oacc[i][0] += pv[i] * vv.x;
        oacc[i][1] += pv[i] * vv.y;
        oacc[i][2] += pv[i] * vv.z;
        oacc[i][3] += pv[i] * vv.w;
      }
    }
  }

  // ---- epilogue: O[row][d] = oacc / l ----
#pragma unroll
  for (int i = 0; i < 4; ++i) {
    const float inv = 1.f / l_run[i];
    const int row = q0 + (ty << 2) + i;
    float4 o = make_float4(oacc[i][0] * inv, oacc[i][1] * inv,
                           oacc[i][2] * inv, oacc[i][3] * inv);
    *(float4*)(O + base + (size_t)row * DMODEL + (tx << 2)) = o;
  }
}

// ---------------------------------------------------------------------------
// out = LayerNorm(X + Y) * w + b   (row = 768, block = 256 threads)
// ---------------------------------------------------------------------------
__global__ __launch_bounds__(256) void add_ln_kernel(
    const float* __restrict__ X,
    const float* __restrict__ Y,
    const float* __restrict__ w,
    const float* __restrict__ bvec,
    float* __restrict__ out)
{
  __shared__ float buf[DMODEL];
  __shared__ float rbuf[8];
  const int tid  = threadIdx.x;
  const int lane = tid & 63, wv = tid >> 6;
  const size_t base = (size_t)blockIdx.x * DMODEL;

  float s = 0.f, s2 = 0.f;
#pragma unroll
  for (int j = tid; j < DMODEL; j += 256) {
    float v = X[base + j] + Y[base + j];
    buf[j] = v; s += v; s2 += v * v;
  }
#pragma unroll
  for (int o = 32; o; o >>= 1) { s += __shfl_xor(s, o); s2 += __shfl_xor(s2, o); }
  if (lane == 0) { rbuf[wv] = s; rbuf[4 + wv] = s2; }
  __syncthreads();
  const float S  = rbuf[0] + rbuf[1] + rbuf[2] + rbuf[3];
  const float S2 = rbuf[4] + rbuf[5] + rbuf[6] + rbuf[7];
  const float mean = S * (1.f / (float)DMODEL);
  const float var  = S2 * (1.f / (float)DMODEL) - mean * mean;
  const float rstd = rsqrtf(var + 1e-5f);
#pragma unroll
  for (int j = tid; j < DMODEL; j += 256) {
    float v = (buf[j] - mean) * rstd * w[j] + bvec[j];
    out[base + j] = v;
  }
}

// ---------------------------------------------------------------------------
extern "C" void kernel_launch(void* const* d_in, const int* in_sizes, int n_in,
                              void* d_out, int out_size, void* d_ws, size_t ws_size,
                              hipStream_t stream) {
  const float* src  = (const float*)d_in[0];
  const float* Wq   = (const float*)d_in[1];
  const float* bq   = (const float*)d_in[2];
  const float* Wk   = (const float*)d_in[3];
  const float* bk   = (const float*)d_in[4];
  const float* Wv   = (const float*)d_in[5];
  const float* bv   = (const float*)d_in[6];
  const float* Wo   = (const float*)d_in[7];
  const float* bo   = (const float*)d_in[8];
  const float* ln1w = (const float*)d_in[9];
  const float* ln1b = (const float*)d_in[10];
  const float* W1   = (const float*)d_in[11];
  const float* b1   = (const float*)d_in[12];
  const float* W2   = (const float*)d_in[13];
  const float* b2   = (const float*)d_in[14];
  const float* ln2w = (const float*)d_in[15];
  const float* ln2b = (const float*)d_in[16];

  // workspace layout, with aliasing:
  //   qb kb vb ctx : 4 x [4096*768] fp32          (50.3 MB)
  //   ff           : [4096*3072] bf16 (ushort)    (25.2 MB)
  //   ao := qb, x1 := kb, y2 := vb  (dead after attention)
  float* ws = (float*)d_ws;
  const size_t SEG = (size_t)MROWS * DMODEL;  // 3.146M elems
  float* qb  = ws;
  float* kb_ = ws + SEG;
  float* vb_ = ws + 2 * SEG;
  float* ctx = ws + 3 * SEG;
  unsigned short* ff = (unsigned short*)(ws + 4 * SEG);  // 4096*3072 bf16
  float* ao  = qb;
  float* x1  = kb_;
  float* y2  = vb_;
  (void)ws_size; (void)in_sizes; (void)n_in; (void)out_size;

  dim3 blk(256);
  dim3 gQKV(DMODEL / 64, MROWS / 64);   // 12 x 64

  // 1-3: QKV projections (head-blocked weights), out layout [B,S,H,DK]
  gemm_kernel<<<gQKV, blk, 0, stream>>>(src, Wq, bq, qb,  DMODEL, DMODEL, 64, DMODEL, 1, 0, 0, 0);
  gemm_kernel<<<gQKV, blk, 0, stream>>>(src, Wk, bk, kb_, DMODEL, DMODEL, 64, DMODEL, 1, 0, 0, 0);
  gemm_kernel<<<gQKV, blk, 0, stream>>>(src, Wv, bv, vb_, DMODEL, DMODEL, 64, DMODEL, 1, 0, 0, 0);

  // 4: flash attention -> ctx [B,S,H*DK]
  dim3 ga(S_LEN / 64, NHEAD, 2);        // 32 x 12 x 2 = 768 blocks
  flash_attn_kernel<<<ga, blk, 0, stream>>>(qb, kb_, vb_, ctx);

  // 5: attn_out = ctx @ Wo + bo
  gemm_kernel<<<gQKV, blk, 0, stream>>>(ctx, Wo, bo, ao, DMODEL, DMODEL, DMODEL, DMODEL, 0, 0, 0, 0);

  // 6: x1 = LN(src + attn_out)
  add_ln_kernel<<<dim3(MROWS), blk, 0, stream>>>(src, ao, ln1w, ln1b, x1);

  // 7: ff = relu(x1 @ W1 + b1), stored bf16
  dim3 gF1(DFF_K / 64, MROWS / 64);     // 48 x 64
  gemm_kernel<<<gF1, blk, 0, stream>>>(x1, W1, b1, ff, DMODEL, DMODEL, DFF_K, DFF_K, 0, 1, 0, 1);

  // 8: y2 = ff @ W2 + b2  (A is bf16)
  gemm_kernel<<<gQKV, blk, 0, stream>>>(ff, W2, b2, y2, DFF_K, DFF_K, DMODEL, DMODEL, 0, 0, 1, 0);

  // 9: out = LN(x1 + y2)
  add_ln_kernel<<<dim3(MROWS), blk, 0, stream>>>(x1, y2, ln2w, ln2b, (float*)d_out);
}

// Round 4
// 791.139 us; speedup vs baseline: 6.2353x; 1.8352x over previous
//
#include <hip/hip_runtime.h>
#include <hip/hip_bf16.h>

#define S_LEN 2048
#define DMODEL 768
#define NHEAD 12
#define DKH 64
#define DFF_K 3072
#define MROWS 4096   // B*S

typedef __attribute__((ext_vector_type(8))) short bf16x8;
typedef __attribute__((ext_vector_type(8))) unsigned short us8;
typedef __attribute__((ext_vector_type(4))) float f32x4;

__device__ __forceinline__ float bfu2f(unsigned short u) {
  return __uint_as_float(((unsigned int)u) << 16);
}
__device__ __forceinline__ unsigned short f2bfu(float f) {
  __hip_bfloat16 h = __float2bfloat16(f);
  return *reinterpret_cast<unsigned short*>(&h);
}

// ---------------------------------------------------------------------------
// fp32 -> bf16 elementwise convert (n multiple of 1024)
// ---------------------------------------------------------------------------
__global__ __launch_bounds__(256) void convert_kernel(
    const float* __restrict__ in, unsigned short* __restrict__ out, int n4)
{
  const int i = blockIdx.x * 256 + threadIdx.x;
  if (i < n4) {
    float4 v = *(const float4*)(in + (size_t)i * 4);
    ushort4 o;
    o.x = f2bfu(v.x); o.y = f2bfu(v.y); o.z = f2bfu(v.z); o.w = f2bfu(v.w);
    *(ushort4*)(out + (size_t)i * 4) = o;
  }
}

// ---------------------------------------------------------------------------
// fp32 [R][C] -> bf16 [C][R] transpose-convert. head mode: in is [H][R][64]
// (per-head stacked), block y = head; out rows y*64.. -> flat [C][R].
// R, C multiples of 64.
// ---------------------------------------------------------------------------
__global__ __launch_bounds__(256) void transpose_conv_kernel(
    const float* __restrict__ in, unsigned short* __restrict__ out,
    int R, int Ctot, int head)
{
  __shared__ float t[64][68];
  const int tid = threadIdx.x;
  const int r0 = blockIdx.x * 64;
  const int c0 = blockIdx.y * 64;
  const float* ib;
  int ld;
  if (head) { ib = in + (size_t)blockIdx.y * R * 64; ld = 64; }
  else      { ib = in + c0;                          ld = Ctot; }
  const int lr = tid >> 4;         // 0..15
  const int lc = (tid & 15) << 2;  // 0..60

#pragma unroll
  for (int rr = 0; rr < 4; ++rr) {
    const int row = rr * 16 + lr;
    float4 v = *(const float4*)(ib + (size_t)(r0 + row) * ld + lc);
    t[row][lc + 0] = v.x; t[row][lc + 1] = v.y;
    t[row][lc + 2] = v.z; t[row][lc + 3] = v.w;
  }
  __syncthreads();
#pragma unroll
  for (int rr = 0; rr < 4; ++rr) {
    const int oc = rr * 16 + lr;
    ushort4 o;
    o.x = f2bfu(t[lc + 0][oc]); o.y = f2bfu(t[lc + 1][oc]);
    o.z = f2bfu(t[lc + 2][oc]); o.w = f2bfu(t[lc + 3][oc]);
    *(ushort4*)(out + (size_t)(c0 + oc) * R + r0 + lc) = o;
  }
}

// ---------------------------------------------------------------------------
// MFMA bf16 GEMM: C[M x N] = act(A[M x K] @ BT[N x K]^T + bias[N]).
// BM=128, BN template (128 or 64). 256 threads = 4 waves; wave tile 64 x WN.
// mfma_f32_16x16x32_bf16; A-frag A[m=lane&15][k=quad*8+j]; B-frag
// B[n=lane&15][k=quad*8+j]; D col=lane&15, row=quad*4+reg.
// ---------------------------------------------------------------------------
template<int BN>
__global__ __launch_bounds__(256) void mfma_gemm_kernel(
    const unsigned short* __restrict__ A,
    const unsigned short* __restrict__ BT,
    const float* __restrict__ bias,
    unsigned short* __restrict__ C,
    int K, int N, int relu)
{
  constexpr int WN = (BN == 128) ? 64 : 32;
  constexpr int NJ = WN / 16;
  __shared__ unsigned short As[128][40];   // +8 pad
  __shared__ unsigned short Bs[BN][40];

  const int tid  = threadIdx.x;
  const int wid  = tid >> 6;
  const int lane = tid & 63;
  const int ml   = lane & 15;
  const int quad = lane >> 4;
  const int wm   = (wid & 1) * 64;
  const int wn   = (wid >> 1) * WN;
  const int row0 = blockIdx.y * 128;
  const int col0 = blockIdx.x * BN;

  const int sr = tid >> 2;         // 0..63
  const int sk = (tid & 3) << 3;   // 0,8,16,24

  f32x4 acc[4][NJ];
#pragma unroll
  for (int i = 0; i < 4; ++i)
#pragma unroll
    for (int j = 0; j < NJ; ++j)
#pragma unroll
      for (int r = 0; r < 4; ++r) acc[i][j][r] = 0.f;

  for (int k0 = 0; k0 < K; k0 += 32) {
    us8 a0 = *(const us8*)(A + (size_t)(row0 + sr) * K + k0 + sk);
    us8 a1 = *(const us8*)(A + (size_t)(row0 + sr + 64) * K + k0 + sk);
    us8 b0 = *(const us8*)(BT + (size_t)(col0 + sr) * K + k0 + sk);
    *(us8*)&As[sr][sk]      = a0;
    *(us8*)&As[sr + 64][sk] = a1;
    *(us8*)&Bs[sr][sk]      = b0;
    if (BN == 128) {
      us8 b1 = *(const us8*)(BT + (size_t)(col0 + sr + 64) * K + k0 + sk);
      *(us8*)&Bs[sr + 64][sk] = b1;
    }
    __syncthreads();

    bf16x8 af[4], bfr[NJ];
#pragma unroll
    for (int i = 0; i < 4; ++i)
      af[i] = *(const bf16x8*)&As[wm + i * 16 + ml][quad << 3];
#pragma unroll
    for (int j = 0; j < NJ; ++j)
      bfr[j] = *(const bf16x8*)&Bs[wn + j * 16 + ml][quad << 3];
#pragma unroll
    for (int i = 0; i < 4; ++i)
#pragma unroll
      for (int j = 0; j < NJ; ++j)
        acc[i][j] = __builtin_amdgcn_mfma_f32_16x16x32_bf16(
            af[i], bfr[j], acc[i][j], 0, 0, 0);
    __syncthreads();
  }

#pragma unroll
  for (int j = 0; j < NJ; ++j) {
    const int col = col0 + wn + j * 16 + ml;
    const float bb = bias[col];
#pragma unroll
    for (int i = 0; i < 4; ++i) {
      const int r0g = row0 + wm + i * 16 + (quad << 2);
#pragma unroll
      for (int r = 0; r < 4; ++r) {
        float v = acc[i][j][r] + bb;
        if (relu) v = fmaxf(v, 0.f);
        C[(size_t)(r0g + r) * N + col] = f2bfu(v);
      }
    }
  }
}

// ---------------------------------------------------------------------------
// Flash attention, bf16 Q/K/V/O in [B,S,H*DK] layout. Block = 64 q-rows of
// one (b,h); 16x16 thread grid, 4x4 tile each. fp32 LDS compute buffers.
// P stored TRANSPOSED (Pst[t][row], stride 68) -> PV reads are float4 +
// broadcast, no 8-way conflicts.
// ---------------------------------------------------------------------------
#define AT_STR 68
__global__ __launch_bounds__(256) void flash_attn_kernel(
    const unsigned short* __restrict__ Q,
    const unsigned short* __restrict__ K,
    const unsigned short* __restrict__ V,
    unsigned short* __restrict__ O)
{
  __shared__ float Qs[64][AT_STR];    // [d][row]
  __shared__ float KsPs[64][AT_STR];  // Ks[d][t] then Pst[t][row]
  __shared__ float Vs[64][64];        // [t][d]

  const int tid = threadIdx.x;
  const int tx  = tid & 15;
  const int ty  = tid >> 4;
  const int b   = blockIdx.z, h = blockIdx.y;
  const int q0  = blockIdx.x * 64;
  const size_t base = (size_t)b * S_LEN * DMODEL + (size_t)h * DKH;

  const int st_r = tid >> 3;         // 0..31
  const int st_c = (tid & 7) << 3;   // 0,8,...,56

  // ---- stage Q tile (transposed into Qs[d][row]) ----
#pragma unroll
  for (int r = 0; r < 2; ++r) {
    const int row = r * 32 + st_r;
    us8 qv = *(const us8*)(Q + base + (size_t)(q0 + row) * DMODEL + st_c);
#pragma unroll
    for (int e = 0; e < 8; ++e)
      Qs[st_c + e][row] = bfu2f((unsigned short)qv[e]);
  }

  float m_run[4] = {-1e30f, -1e30f, -1e30f, -1e30f};
  float l_run[4] = {0.f, 0.f, 0.f, 0.f};
  float oacc[4][4] = {{0.f,0.f,0.f,0.f},{0.f,0.f,0.f,0.f},
                      {0.f,0.f,0.f,0.f},{0.f,0.f,0.f,0.f}};

  for (int kt = 0; kt < S_LEN; kt += 64) {
    __syncthreads();

    // ---- stage K (-> Ks[d][t]) and V (-> Vs[t][d]) ----
#pragma unroll
    for (int r = 0; r < 2; ++r) {
      const int t = r * 32 + st_r;
      const size_t g = base + (size_t)(kt + t) * DMODEL + st_c;
      us8 kv = *(const us8*)(K + g);
      us8 vv = *(const us8*)(V + g);
#pragma unroll
      for (int e = 0; e < 8; ++e)
        KsPs[st_c + e][t] = bfu2f((unsigned short)kv[e]);
      float4 f0 = make_float4(bfu2f((unsigned short)vv[0]), bfu2f((unsigned short)vv[1]),
                              bfu2f((unsigned short)vv[2]), bfu2f((unsigned short)vv[3]));
      float4 f1 = make_float4(bfu2f((unsigned short)vv[4]), bfu2f((unsigned short)vv[5]),
                              bfu2f((unsigned short)vv[6]), bfu2f((unsigned short)vv[7]));
      *(float4*)&Vs[t][st_c]     = f0;
      *(float4*)&Vs[t][st_c + 4] = f1;
    }
    __syncthreads();

    // ---- S tile ----
    float s[4][4] = {{0.f,0.f,0.f,0.f},{0.f,0.f,0.f,0.f},
                     {0.f,0.f,0.f,0.f},{0.f,0.f,0.f,0.f}};
#pragma unroll
    for (int dd = 0; dd < 64; ++dd) {
      float4 qv = *(const float4*)&Qs[dd][ty << 2];    // broadcast
      float4 kv = *(const float4*)&KsPs[dd][tx << 2];  // 2-way (free)
      float qq[4] = {qv.x, qv.y, qv.z, qv.w};
      float kk[4] = {kv.x, kv.y, kv.z, kv.w};
#pragma unroll
      for (int i = 0; i < 4; ++i)
#pragma unroll
        for (int j = 0; j < 4; ++j)
          s[i][j] += qq[i] * kk[j];
    }

    // ---- online softmax ----
    float p[4][4];
#pragma unroll
    for (int i = 0; i < 4; ++i) {
      float mt = fmaxf(fmaxf(s[i][0], s[i][1]), fmaxf(s[i][2], s[i][3])) * 0.125f;
#pragma unroll
      for (int o = 8; o; o >>= 1) mt = fmaxf(mt, __shfl_xor(mt, o));
      const float m_new = fmaxf(m_run[i], mt);
      const float alpha = __expf(m_run[i] - m_new);
      float rs = 0.f;
#pragma unroll
      for (int j = 0; j < 4; ++j) {
        p[i][j] = __expf(s[i][j] * 0.125f - m_new);
        rs += p[i][j];
      }
#pragma unroll
      for (int o = 8; o; o >>= 1) rs += __shfl_xor(rs, o);
      l_run[i] = l_run[i] * alpha + rs;
      m_run[i] = m_new;
#pragma unroll
      for (int j = 0; j < 4; ++j) oacc[i][j] *= alpha;
    }

    __syncthreads();  // Ks reads done -> overwrite with Pst

    // ---- write P transposed: Pst[t=4tx+j][row 4ty..4ty+3] ----
#pragma unroll
    for (int j = 0; j < 4; ++j)
      *(float4*)&KsPs[(tx << 2) + j][ty << 2] =
          make_float4(p[0][j], p[1][j], p[2][j], p[3][j]);
    __syncthreads();

    // ---- PV ----
#pragma unroll
    for (int t = 0; t < 64; ++t) {
      float4 vv = *(const float4*)&Vs[t][tx << 2];    // 2-way (free)
      float4 pp = *(const float4*)&KsPs[t][ty << 2];  // broadcast, float4
      float pv[4] = {pp.x, pp.y, pp.z, pp.w};
#pragma unroll
      for (int i = 0; i < 4; ++i) {
        oacc[i][0] += pv[i] * vv.x;
        oacc[i][1] += pv[i] * vv.y;
        oacc[i][2] += pv[i] * vv.z;
        oacc[i][3] += pv[i] * vv.w;
      }
    }
  }

  // ---- epilogue ----
#pragma unroll
  for (int i = 0; i < 4; ++i) {
    const float inv = 1.f / l_run[i];
    const int row = q0 + (ty << 2) + i;
    ushort4 o;
    o.x = f2bfu(oacc[i][0] * inv); o.y = f2bfu(oacc[i][1] * inv);
    o.z = f2bfu(oacc[i][2] * inv); o.w = f2bfu(oacc[i][3] * inv);
    *(ushort4*)(O + base + (size_t)row * DMODEL + (tx << 2)) = o;
  }
}

// ---------------------------------------------------------------------------
// out = LayerNorm(X + Y) * w + b; X/Y/out dtype per flags (1 = bf16)
// ---------------------------------------------------------------------------
__global__ __launch_bounds__(256) void add_ln_kernel(
    const void* __restrict__ X, const void* __restrict__ Y,
    const float* __restrict__ w, const float* __restrict__ bvec,
    void* __restrict__ out, int xbf, int ybf, int obf)
{
  __shared__ float buf[DMODEL];
  __shared__ float rbuf[8];
  const int tid  = threadIdx.x;
  const int lane = tid & 63, wv = tid >> 6;
  const size_t base = (size_t)blockIdx.x * DMODEL;

  float s = 0.f, s2 = 0.f;
#pragma unroll
  for (int j = tid; j < DMODEL; j += 256) {
    float xv = xbf ? bfu2f(((const unsigned short*)X)[base + j])
                   : ((const float*)X)[base + j];
    float yv = ybf ? bfu2f(((const unsigned short*)Y)[base + j])
                   : ((const float*)Y)[base + j];
    float v = xv + yv;
    buf[j] = v; s += v; s2 += v * v;
  }
#pragma unroll
  for (int o = 32; o; o >>= 1) { s += __shfl_xor(s, o); s2 += __shfl_xor(s2, o); }
  if (lane == 0) { rbuf[wv] = s; rbuf[4 + wv] = s2; }
  __syncthreads();
  const float S  = rbuf[0] + rbuf[1] + rbuf[2] + rbuf[3];
  const float S2 = rbuf[4] + rbuf[5] + rbuf[6] + rbuf[7];
  const float mean = S * (1.f / (float)DMODEL);
  const float var  = S2 * (1.f / (float)DMODEL) - mean * mean;
  const float rstd = rsqrtf(var + 1e-5f);
#pragma unroll
  for (int j = tid; j < DMODEL; j += 256) {
    float v = (buf[j] - mean) * rstd * w[j] + bvec[j];
    if (obf) ((unsigned short*)out)[base + j] = f2bfu(v);
    else     ((float*)out)[base + j] = v;
  }
}

// ---------------------------------------------------------------------------
extern "C" void kernel_launch(void* const* d_in, const int* in_sizes, int n_in,
                              void* d_out, int out_size, void* d_ws, size_t ws_size,
                              hipStream_t stream) {
  const float* src  = (const float*)d_in[0];
  const float* Wq   = (const float*)d_in[1];
  const float* bq   = (const float*)d_in[2];
  const float* Wk   = (const float*)d_in[3];
  const float* bk   = (const float*)d_in[4];
  const float* Wv   = (const float*)d_in[5];
  const float* bv   = (const float*)d_in[6];
  const float* Wo   = (const float*)d_in[7];
  const float* bo   = (const float*)d_in[8];
  const float* ln1w = (const float*)d_in[9];
  const float* ln1b = (const float*)d_in[10];
  const float* W1   = (const float*)d_in[11];
  const float* b1   = (const float*)d_in[12];
  const float* W2   = (const float*)d_in[13];
  const float* b2   = (const float*)d_in[14];
  const float* ln2w = (const float*)d_in[15];
  const float* ln2b = (const float*)d_in[16];
  (void)ws_size; (void)in_sizes; (void)n_in; (void)out_size;

  // workspace (bf16 elements), ~71 MB total
  unsigned short* p = (unsigned short*)d_ws;
  const size_t SEG = (size_t)MROWS * DMODEL;   // 3.146M
  unsigned short* srcb = p; p += SEG;
  unsigned short* qb   = p; p += SEG;
  unsigned short* kb_  = p; p += SEG;
  unsigned short* vb_  = p; p += SEG;
  unsigned short* ctx  = p; p += SEG;
  unsigned short* ff   = p; p += (size_t)MROWS * DFF_K;
  unsigned short* wqt  = p; p += (size_t)DMODEL * DMODEL;
  unsigned short* wkt  = p; p += (size_t)DMODEL * DMODEL;
  unsigned short* wvt  = p; p += (size_t)DMODEL * DMODEL;
  unsigned short* wot  = p; p += (size_t)DMODEL * DMODEL;
  unsigned short* w1t  = p; p += (size_t)DMODEL * DFF_K;
  unsigned short* w2t  = p; p += (size_t)DMODEL * DFF_K;
  unsigned short* ao = qb;   // aliases (dead after attention)
  unsigned short* x1 = kb_;
  unsigned short* y2 = vb_;

  dim3 blk(256);

  // 0: conversions
  convert_kernel<<<dim3(SEG / 1024), blk, 0, stream>>>(src, srcb, (int)(SEG / 4));
  transpose_conv_kernel<<<dim3(12, 12), blk, 0, stream>>>(Wq, wqt, DMODEL, DMODEL, 1);
  transpose_conv_kernel<<<dim3(12, 12), blk, 0, stream>>>(Wk, wkt, DMODEL, DMODEL, 1);
  transpose_conv_kernel<<<dim3(12, 12), blk, 0, stream>>>(Wv, wvt, DMODEL, DMODEL, 1);
  transpose_conv_kernel<<<dim3(12, 12), blk, 0, stream>>>(Wo, wot, DMODEL, DMODEL, 0);
  transpose_conv_kernel<<<dim3(12, 48), blk, 0, stream>>>(W1, w1t, DMODEL, DFF_K, 0);
  transpose_conv_kernel<<<dim3(48, 12), blk, 0, stream>>>(W2, w2t, DFF_K, DMODEL, 0);

  // 1-3: QKV projections  (transposed per-head weights are plain [N][K])
  dim3 g768(DMODEL / 64, MROWS / 128);   // 12 x 32
  mfma_gemm_kernel<64><<<g768, blk, 0, stream>>>(srcb, wqt, bq, qb,  DMODEL, DMODEL, 0);
  mfma_gemm_kernel<64><<<g768, blk, 0, stream>>>(srcb, wkt, bk, kb_, DMODEL, DMODEL, 0);
  mfma_gemm_kernel<64><<<g768, blk, 0, stream>>>(srcb, wvt, bv, vb_, DMODEL, DMODEL, 0);

  // 4: flash attention -> ctx
  dim3 ga(S_LEN / 64, NHEAD, 2);
  flash_attn_kernel<<<ga, blk, 0, stream>>>(qb, kb_, vb_, ctx);

  // 5: attn_out = ctx @ Wo + bo
  mfma_gemm_kernel<64><<<g768, blk, 0, stream>>>(ctx, wot, bo, ao, DMODEL, DMODEL, 0);

  // 6: x1 = LN(src + attn_out)
  add_ln_kernel<<<dim3(MROWS), blk, 0, stream>>>(src, ao, ln1w, ln1b, x1, 0, 1, 1);

  // 7: ff = relu(x1 @ W1 + b1)
  dim3 gF1(DFF_K / 128, MROWS / 128);    // 24 x 32
  mfma_gemm_kernel<128><<<gF1, blk, 0, stream>>>(x1, w1t, b1, ff, DMODEL, DFF_K, 1);

  // 8: y2 = ff @ W2 + b2
  mfma_gemm_kernel<64><<<g768, blk, 0, stream>>>(ff, w2t, b2, y2, DFF_K, DMODEL, 0);

  // 9: out = LN(x1 + y2)
  add_ln_kernel<<<dim3(MROWS), blk, 0, stream>>>(x1, y2, ln2w, ln2b, (float*)d_out, 1, 1, 0);
}

// Round 5
// 394.685 us; speedup vs baseline: 12.4986x; 2.0045x over previous
//
#include <hip/hip_runtime.h>
#include <hip/hip_bf16.h>

#define S_LEN 2048
#define DMODEL 768
#define NHEAD 12
#define DKH 64
#define DFF_K 3072
#define MROWS 4096   // B*S

typedef __attribute__((ext_vector_type(8))) short bf16x8;
typedef __attribute__((ext_vector_type(8))) unsigned short us8;
typedef __attribute__((ext_vector_type(4))) float f32x4;

__device__ __forceinline__ float bfu2f(unsigned short u) {
  return __uint_as_float(((unsigned int)u) << 16);
}
__device__ __forceinline__ unsigned short f2bfu(float f) {
  __hip_bfloat16 h = __float2bfloat16(f);
  return *reinterpret_cast<unsigned short*>(&h);
}

// ---------------------------------------------------------------------------
// fp32 -> bf16 elementwise convert
// ---------------------------------------------------------------------------
__global__ __launch_bounds__(256) void convert_kernel(
    const float* __restrict__ in, unsigned short* __restrict__ out, int n4)
{
  const int i = blockIdx.x * 256 + threadIdx.x;
  if (i < n4) {
    float4 v = *(const float4*)(in + (size_t)i * 4);
    ushort4 o;
    o.x = f2bfu(v.x); o.y = f2bfu(v.y); o.z = f2bfu(v.z); o.w = f2bfu(v.w);
    *(ushort4*)(out + (size_t)i * 4) = o;
  }
}

// ---------------------------------------------------------------------------
// fp32 [R][C] -> bf16 [C][R] transpose-convert (generic, head or flat).
// ---------------------------------------------------------------------------
__device__ __forceinline__ void transpose_conv_body(
    const float* in, unsigned short* out, int R, int Ctot, int head,
    int bx, int by, int tid)
{
  __shared__ float t[64][68];
  const int r0 = bx * 64;
  const int c0 = by * 64;
  const float* ib;
  int ld;
  if (head) { ib = in + (size_t)by * R * 64; ld = 64; }
  else      { ib = in + c0;                  ld = Ctot; }
  const int lr = tid >> 4;
  const int lc = (tid & 15) << 2;

#pragma unroll
  for (int rr = 0; rr < 4; ++rr) {
    const int row = rr * 16 + lr;
    float4 v = *(const float4*)(ib + (size_t)(r0 + row) * ld + lc);
    t[row][lc + 0] = v.x; t[row][lc + 1] = v.y;
    t[row][lc + 2] = v.z; t[row][lc + 3] = v.w;
  }
  __syncthreads();
#pragma unroll
  for (int rr = 0; rr < 4; ++rr) {
    const int oc = rr * 16 + lr;
    ushort4 o;
    o.x = f2bfu(t[lc + 0][oc]); o.y = f2bfu(t[lc + 1][oc]);
    o.z = f2bfu(t[lc + 2][oc]); o.w = f2bfu(t[lc + 3][oc]);
    *(ushort4*)(out + (size_t)(c0 + oc) * R + r0 + lc) = o;
  }
}

__global__ __launch_bounds__(256) void transpose_conv_kernel(
    const float* __restrict__ in, unsigned short* __restrict__ out,
    int R, int Ctot, int head)
{
  transpose_conv_body(in, out, R, Ctot, head, blockIdx.x, blockIdx.y, threadIdx.x);
}

// fused QKV weight transpose: z selects tensor (all head-mode, 768x768)
__global__ __launch_bounds__(256) void transpose_conv3_kernel(
    const float* __restrict__ i0, const float* __restrict__ i1,
    const float* __restrict__ i2, unsigned short* __restrict__ o0,
    unsigned short* __restrict__ o1, unsigned short* __restrict__ o2)
{
  const int z = blockIdx.z;
  const float* in = (z == 0) ? i0 : (z == 1) ? i1 : i2;
  unsigned short* out = (z == 0) ? o0 : (z == 1) ? o1 : o2;
  transpose_conv_body(in, out, DMODEL, DMODEL, 1, blockIdx.x, blockIdx.y, threadIdx.x);
}

// ---------------------------------------------------------------------------
// MFMA bf16 GEMM: C = act(A[M x K] @ BT[N x K]^T + bias). BM=128.
// store_vt: write C transposed per-(b,h) as VT[b,h,d,s] (for attention V).
// ---------------------------------------------------------------------------
template<int BN>
__global__ __launch_bounds__(256) void mfma_gemm_kernel(
    const unsigned short* __restrict__ A,
    const unsigned short* __restrict__ BT,
    const float* __restrict__ bias,
    unsigned short* __restrict__ C,
    int K, int N, int relu, int store_vt)
{
  constexpr int WN = (BN == 128) ? 64 : 32;
  constexpr int NJ = WN / 16;
  __shared__ unsigned short As[128][40];
  __shared__ unsigned short Bs[BN][40];

  const int tid  = threadIdx.x;
  const int wid  = tid >> 6;
  const int lane = tid & 63;
  const int ml   = lane & 15;
  const int quad = lane >> 4;
  const int wm   = (wid & 1) * 64;
  const int wn   = (wid >> 1) * WN;
  const int row0 = blockIdx.y * 128;
  const int col0 = blockIdx.x * BN;

  const int sr = tid >> 2;
  const int sk = (tid & 3) << 3;

  f32x4 acc[4][NJ];
#pragma unroll
  for (int i = 0; i < 4; ++i)
#pragma unroll
    for (int j = 0; j < NJ; ++j)
#pragma unroll
      for (int r = 0; r < 4; ++r) acc[i][j][r] = 0.f;

  for (int k0 = 0; k0 < K; k0 += 32) {
    us8 a0 = *(const us8*)(A + (size_t)(row0 + sr) * K + k0 + sk);
    us8 a1 = *(const us8*)(A + (size_t)(row0 + sr + 64) * K + k0 + sk);
    us8 b0 = *(const us8*)(BT + (size_t)(col0 + sr) * K + k0 + sk);
    *(us8*)&As[sr][sk]      = a0;
    *(us8*)&As[sr + 64][sk] = a1;
    *(us8*)&Bs[sr][sk]      = b0;
    if (BN == 128) {
      us8 b1 = *(const us8*)(BT + (size_t)(col0 + sr + 64) * K + k0 + sk);
      *(us8*)&Bs[sr + 64][sk] = b1;
    }
    __syncthreads();

    bf16x8 af[4], bfr[NJ];
#pragma unroll
    for (int i = 0; i < 4; ++i)
      af[i] = *(const bf16x8*)&As[wm + i * 16 + ml][quad << 3];
#pragma unroll
    for (int j = 0; j < NJ; ++j)
      bfr[j] = *(const bf16x8*)&Bs[wn + j * 16 + ml][quad << 3];
#pragma unroll
    for (int i = 0; i < 4; ++i)
#pragma unroll
      for (int j = 0; j < NJ; ++j)
        acc[i][j] = __builtin_amdgcn_mfma_f32_16x16x32_bf16(
            af[i], bfr[j], acc[i][j], 0, 0, 0);
    __syncthreads();
  }

#pragma unroll
  for (int j = 0; j < NJ; ++j) {
    const int col = col0 + wn + j * 16 + ml;
    const float bb = bias[col];
#pragma unroll
    for (int i = 0; i < 4; ++i) {
      const int r0g = row0 + wm + i * 16 + (quad << 2);
      if (store_vt) {
        const int bb_ = r0g >> 11, s = r0g & 2047;
        const int hh = col >> 6, dd = col & 63;
        ushort4 o;
        o.x = f2bfu(acc[i][j][0] + bb); o.y = f2bfu(acc[i][j][1] + bb);
        o.z = f2bfu(acc[i][j][2] + bb); o.w = f2bfu(acc[i][j][3] + bb);
        *(ushort4*)(C + ((size_t)((bb_ * NHEAD + hh) * DKH + dd)) * S_LEN + s) = o;
      } else {
#pragma unroll
        for (int r = 0; r < 4; ++r) {
          float v = acc[i][j][r] + bb;
          if (relu) v = fmaxf(v, 0.f);
          C[(size_t)(r0g + r) * N + col] = f2bfu(v);
        }
      }
    }
  }
}

// fused QKV projection: z=0 -> Q, z=1 -> K, z=2 -> V (VT store). BN=64.
__global__ __launch_bounds__(256) void qkv_gemm_kernel(
    const unsigned short* __restrict__ A,
    const unsigned short* __restrict__ W0, const unsigned short* __restrict__ W1,
    const unsigned short* __restrict__ W2,
    const float* __restrict__ bq, const float* __restrict__ bk,
    const float* __restrict__ bv,
    unsigned short* __restrict__ C0, unsigned short* __restrict__ C1,
    unsigned short* __restrict__ C2)
{
  __shared__ unsigned short As[128][40];
  __shared__ unsigned short Bs[64][40];
  const int z = blockIdx.z;
  const unsigned short* BT = (z == 0) ? W0 : (z == 1) ? W1 : W2;
  const float* bias = (z == 0) ? bq : (z == 1) ? bk : bv;
  unsigned short* C = (z == 0) ? C0 : (z == 1) ? C1 : C2;
  const int K = DMODEL, N = DMODEL;

  const int tid  = threadIdx.x;
  const int wid  = tid >> 6;
  const int lane = tid & 63;
  const int ml   = lane & 15;
  const int quad = lane >> 4;
  const int wm   = (wid & 1) * 64;
  const int wn   = (wid >> 1) * 32;
  const int row0 = blockIdx.y * 128;
  const int col0 = blockIdx.x * 64;
  const int sr = tid >> 2;
  const int sk = (tid & 3) << 3;

  f32x4 acc[4][2];
#pragma unroll
  for (int i = 0; i < 4; ++i)
#pragma unroll
    for (int j = 0; j < 2; ++j)
#pragma unroll
      for (int r = 0; r < 4; ++r) acc[i][j][r] = 0.f;

  for (int k0 = 0; k0 < K; k0 += 32) {
    us8 a0 = *(const us8*)(A + (size_t)(row0 + sr) * K + k0 + sk);
    us8 a1 = *(const us8*)(A + (size_t)(row0 + sr + 64) * K + k0 + sk);
    us8 b0 = *(const us8*)(BT + (size_t)(col0 + sr) * K + k0 + sk);
    *(us8*)&As[sr][sk]      = a0;
    *(us8*)&As[sr + 64][sk] = a1;
    *(us8*)&Bs[sr][sk]      = b0;
    __syncthreads();
    bf16x8 af[4], bfr[2];
#pragma unroll
    for (int i = 0; i < 4; ++i)
      af[i] = *(const bf16x8*)&As[wm + i * 16 + ml][quad << 3];
#pragma unroll
    for (int j = 0; j < 2; ++j)
      bfr[j] = *(const bf16x8*)&Bs[wn + j * 16 + ml][quad << 3];
#pragma unroll
    for (int i = 0; i < 4; ++i)
#pragma unroll
      for (int j = 0; j < 2; ++j)
        acc[i][j] = __builtin_amdgcn_mfma_f32_16x16x32_bf16(
            af[i], bfr[j], acc[i][j], 0, 0, 0);
    __syncthreads();
  }

#pragma unroll
  for (int j = 0; j < 2; ++j) {
    const int col = col0 + wn + j * 16 + ml;
    const float bb = bias[col];
#pragma unroll
    for (int i = 0; i < 4; ++i) {
      const int r0g = row0 + wm + i * 16 + (quad << 2);
      if (z == 2) {
        const int bb_ = r0g >> 11, s = r0g & 2047;
        const int hh = col >> 6, dd = col & 63;
        ushort4 o;
        o.x = f2bfu(acc[i][j][0] + bb); o.y = f2bfu(acc[i][j][1] + bb);
        o.z = f2bfu(acc[i][j][2] + bb); o.w = f2bfu(acc[i][j][3] + bb);
        *(ushort4*)(C + ((size_t)((bb_ * NHEAD + hh) * DKH + dd)) * S_LEN + s) = o;
      } else {
#pragma unroll
        for (int r = 0; r < 4; ++r)
          C[(size_t)(r0g + r) * N + col] = f2bfu(acc[i][j][r] + bb);
      }
    }
  }
}

// ---------------------------------------------------------------------------
// MFMA flash attention. Block = 64 q-rows of one (b,h), 4 waves x 16 q-rows.
// Q,K bf16 [b,s,h*64]; VT bf16 [b,h,64,2048]; O bf16 [b,s,h*64].
// S = Q@K^T via mfma (A=Q-frag, B=K-frag); softmax in C-layout (lane owns
// rows quad*4+reg, col ml; stats via 16-lane quad-group shuffles); P goes
// C-layout -> A-layout through per-wave private LDS (no barrier needed);
// PV via mfma with B-frags from VT tile. LDS 36.9 KB -> 4 blocks/CU.
// ---------------------------------------------------------------------------
#define FATS 72
__global__ __launch_bounds__(256) void flash_attn_mfma(
    const unsigned short* __restrict__ Q,
    const unsigned short* __restrict__ K,
    const unsigned short* __restrict__ VT,
    unsigned short* __restrict__ O)
{
  __shared__ unsigned short Qs[64][FATS];
  __shared__ unsigned short Ks[64][FATS];
  __shared__ unsigned short Vs[64][FATS];      // VT tile: [d][t_local]
  __shared__ unsigned short Ps[4][16][FATS];   // per-wave P: [m][t_local]

  const int tid  = threadIdx.x;
  const int wid  = tid >> 6;
  const int lane = tid & 63;
  const int ml   = lane & 15;
  const int quad = lane >> 4;
  const int b    = blockIdx.z, h = blockIdx.y;
  const int q0   = blockIdx.x * 64;

  const size_t qkbase = ((size_t)b * S_LEN) * DMODEL + (size_t)h * DKH;
  const size_t vtbase = ((size_t)(b * NHEAD + h)) * DKH * S_LEN;

  const int sr = tid >> 2;          // 0..63
  const int sc = (tid & 3) << 4;    // 0,16,32,48

  // ---- stage Q (natural [m][d]) ----
  {
    const unsigned short* qp = Q + qkbase + (size_t)(q0 + sr) * DMODEL + sc;
    *(us8*)&Qs[sr][sc]     = *(const us8*)qp;
    *(us8*)&Qs[sr][sc + 8] = *(const us8*)(qp + 8);
  }
  __syncthreads();

  bf16x8 qf[2];
  qf[0] = *(const bf16x8*)&Qs[wid * 16 + ml][quad << 3];
  qf[1] = *(const bf16x8*)&Qs[wid * 16 + ml][32 + (quad << 3)];

  float m_run[4] = {-1e30f, -1e30f, -1e30f, -1e30f};
  float l_run[4] = {0.f, 0.f, 0.f, 0.f};
  f32x4 oacc[4];
#pragma unroll
  for (int dt = 0; dt < 4; ++dt)
#pragma unroll
    for (int r = 0; r < 4; ++r) oacc[dt][r] = 0.f;

  for (int kt = 0; kt < S_LEN; kt += 64) {
    __syncthreads();   // prior tile's Ks/Vs readers done
    {
      const unsigned short* kp = K + qkbase + (size_t)(kt + sr) * DMODEL + sc;
      *(us8*)&Ks[sr][sc]     = *(const us8*)kp;
      *(us8*)&Ks[sr][sc + 8] = *(const us8*)(kp + 8);
      const unsigned short* vp = VT + vtbase + (size_t)sr * S_LEN + kt + sc;
      *(us8*)&Vs[sr][sc]     = *(const us8*)vp;
      *(us8*)&Vs[sr][sc + 8] = *(const us8*)(vp + 8);
    }
    __syncthreads();

    // ---- S tile: 4 n-tiles x 2 k-chunks ----
    f32x4 sacc[4];
#pragma unroll
    for (int nt = 0; nt < 4; ++nt)
#pragma unroll
      for (int r = 0; r < 4; ++r) sacc[nt][r] = 0.f;
#pragma unroll
    for (int nt = 0; nt < 4; ++nt) {
      bf16x8 kf0 = *(const bf16x8*)&Ks[nt * 16 + ml][quad << 3];
      bf16x8 kf1 = *(const bf16x8*)&Ks[nt * 16 + ml][32 + (quad << 3)];
      sacc[nt] = __builtin_amdgcn_mfma_f32_16x16x32_bf16(qf[0], kf0, sacc[nt], 0, 0, 0);
      sacc[nt] = __builtin_amdgcn_mfma_f32_16x16x32_bf16(qf[1], kf1, sacc[nt], 0, 0, 0);
    }

    // ---- online softmax (C-layout; stats across quad-group lanes) ----
    float mnew[4], alpha[4];
#pragma unroll
    for (int r = 0; r < 4; ++r) {
      float mt = fmaxf(fmaxf(sacc[0][r], sacc[1][r]),
                       fmaxf(sacc[2][r], sacc[3][r])) * 0.125f;
#pragma unroll
      for (int o = 8; o; o >>= 1) mt = fmaxf(mt, __shfl_xor(mt, o));
      mnew[r]  = fmaxf(m_run[r], mt);
      alpha[r] = __expf(m_run[r] - mnew[r]);
      m_run[r] = mnew[r];
    }
    float rs[4] = {0.f, 0.f, 0.f, 0.f};
    float pv[4][4];
#pragma unroll
    for (int nt = 0; nt < 4; ++nt)
#pragma unroll
      for (int r = 0; r < 4; ++r) {
        float e = __expf(sacc[nt][r] * 0.125f - mnew[r]);
        pv[nt][r] = e;
        rs[r] += e;
      }
#pragma unroll
    for (int r = 0; r < 4; ++r) {
#pragma unroll
      for (int o = 8; o; o >>= 1) rs[r] += __shfl_xor(rs[r], o);
      l_run[r] = l_run[r] * alpha[r] + rs[r];
    }
#pragma unroll
    for (int dt = 0; dt < 4; ++dt)
#pragma unroll
      for (int r = 0; r < 4; ++r) oacc[dt][r] *= alpha[r];

    // ---- P: C-layout -> A-layout via per-wave LDS (same-wave, no barrier) ----
#pragma unroll
    for (int nt = 0; nt < 4; ++nt)
#pragma unroll
      for (int r = 0; r < 4; ++r)
        Ps[wid][(quad << 2) + r][nt * 16 + ml] = f2bfu(pv[nt][r]);

    bf16x8 pf0 = *(const bf16x8*)&Ps[wid][ml][quad << 3];
    bf16x8 pf1 = *(const bf16x8*)&Ps[wid][ml][32 + (quad << 3)];

    // ---- PV: O += P @ V  (B-frag rows from VT tile) ----
#pragma unroll
    for (int dt = 0; dt < 4; ++dt) {
      bf16x8 vf0 = *(const bf16x8*)&Vs[dt * 16 + ml][quad << 3];
      bf16x8 vf1 = *(const bf16x8*)&Vs[dt * 16 + ml][32 + (quad << 3)];
      oacc[dt] = __builtin_amdgcn_mfma_f32_16x16x32_bf16(pf0, vf0, oacc[dt], 0, 0, 0);
      oacc[dt] = __builtin_amdgcn_mfma_f32_16x16x32_bf16(pf1, vf1, oacc[dt], 0, 0, 0);
    }
  }

  // ---- epilogue: O[m][d] = oacc / l ----
#pragma unroll
  for (int dt = 0; dt < 4; ++dt) {
#pragma unroll
    for (int r = 0; r < 4; ++r) {
      const float v = oacc[dt][r] / l_run[(size_t)r];
      const int row = q0 + wid * 16 + (quad << 2) + r;
      O[qkbase + (size_t)row * DMODEL + dt * 16 + ml] = f2bfu(v);
    }
  }
}

// ---------------------------------------------------------------------------
// out = LayerNorm(X + Y) * w + b; dtype flags (1 = bf16)
// ---------------------------------------------------------------------------
__global__ __launch_bounds__(256) void add_ln_kernel(
    const void* __restrict__ X, const void* __restrict__ Y,
    const float* __restrict__ w, const float* __restrict__ bvec,
    void* __restrict__ out, int xbf, int ybf, int obf)
{
  __shared__ float buf[DMODEL];
  __shared__ float rbuf[8];
  const int tid  = threadIdx.x;
  const int lane = tid & 63, wv = tid >> 6;
  const size_t base = (size_t)blockIdx.x * DMODEL;

  float s = 0.f, s2 = 0.f;
#pragma unroll
  for (int j = tid; j < DMODEL; j += 256) {
    float xv = xbf ? bfu2f(((const unsigned short*)X)[base + j])
                   : ((const float*)X)[base + j];
    float yv = ybf ? bfu2f(((const unsigned short*)Y)[base + j])
                   : ((const float*)Y)[base + j];
    float v = xv + yv;
    buf[j] = v; s += v; s2 += v * v;
  }
#pragma unroll
  for (int o = 32; o; o >>= 1) { s += __shfl_xor(s, o); s2 += __shfl_xor(s2, o); }
  if (lane == 0) { rbuf[wv] = s; rbuf[4 + wv] = s2; }
  __syncthreads();
  const float S  = rbuf[0] + rbuf[1] + rbuf[2] + rbuf[3];
  const float S2 = rbuf[4] + rbuf[5] + rbuf[6] + rbuf[7];
  const float mean = S * (1.f / (float)DMODEL);
  const float var  = S2 * (1.f / (float)DMODEL) - mean * mean;
  const float rstd = rsqrtf(var + 1e-5f);
#pragma unroll
  for (int j = tid; j < DMODEL; j += 256) {
    float v = (buf[j] - mean) * rstd * w[j] + bvec[j];
    if (obf) ((unsigned short*)out)[base + j] = f2bfu(v);
    else     ((float*)out)[base + j] = v;
  }
}

// ---------------------------------------------------------------------------
extern "C" void kernel_launch(void* const* d_in, const int* in_sizes, int n_in,
                              void* d_out, int out_size, void* d_ws, size_t ws_size,
                              hipStream_t stream) {
  const float* src  = (const float*)d_in[0];
  const float* Wq   = (const float*)d_in[1];
  const float* bq   = (const float*)d_in[2];
  const float* Wk   = (const float*)d_in[3];
  const float* bk   = (const float*)d_in[4];
  const float* Wv   = (const float*)d_in[5];
  const float* bv   = (const float*)d_in[6];
  const float* Wo   = (const float*)d_in[7];
  const float* bo   = (const float*)d_in[8];
  const float* ln1w = (const float*)d_in[9];
  const float* ln1b = (const float*)d_in[10];
  const float* W1   = (const float*)d_in[11];
  const float* b1   = (const float*)d_in[12];
  const float* W2   = (const float*)d_in[13];
  const float* b2   = (const float*)d_in[14];
  const float* ln2w = (const float*)d_in[15];
  const float* ln2b = (const float*)d_in[16];
  (void)ws_size; (void)in_sizes; (void)n_in; (void)out_size;

  unsigned short* p = (unsigned short*)d_ws;
  const size_t SEG = (size_t)MROWS * DMODEL;
  unsigned short* srcb = p; p += SEG;
  unsigned short* qb   = p; p += SEG;
  unsigned short* kb_  = p; p += SEG;
  unsigned short* vbT  = p; p += SEG;          // [b,h,64,2048]
  unsigned short* ctx  = p; p += SEG;
  unsigned short* ff   = p; p += (size_t)MROWS * DFF_K;
  unsigned short* wqt  = p; p += (size_t)DMODEL * DMODEL;
  unsigned short* wkt  = p; p += (size_t)DMODEL * DMODEL;
  unsigned short* wvt  = p; p += (size_t)DMODEL * DMODEL;
  unsigned short* wot  = p; p += (size_t)DMODEL * DMODEL;
  unsigned short* w1t  = p; p += (size_t)DMODEL * DFF_K;
  unsigned short* w2t  = p; p += (size_t)DMODEL * DFF_K;
  unsigned short* ao = qb;
  unsigned short* x1 = kb_;
  unsigned short* y2 = vbT;

  dim3 blk(256);

  // 0: conversions
  convert_kernel<<<dim3(SEG / 1024), blk, 0, stream>>>(src, srcb, (int)(SEG / 4));
  transpose_conv3_kernel<<<dim3(12, 12, 3), blk, 0, stream>>>(Wq, Wk, Wv, wqt, wkt, wvt);
  transpose_conv_kernel<<<dim3(12, 12), blk, 0, stream>>>(Wo, wot, DMODEL, DMODEL, 0);
  transpose_conv_kernel<<<dim3(12, 48), blk, 0, stream>>>(W1, w1t, DMODEL, DFF_K, 0);
  transpose_conv_kernel<<<dim3(48, 12), blk, 0, stream>>>(W2, w2t, DFF_K, DMODEL, 0);

  // 1: fused QKV projections (V written transposed per head)
  dim3 gqkv(DMODEL / 64, MROWS / 128, 3);
  qkv_gemm_kernel<<<gqkv, blk, 0, stream>>>(srcb, wqt, wkt, wvt, bq, bk, bv,
                                            qb, kb_, vbT);

  // 2: MFMA flash attention -> ctx
  dim3 ga(S_LEN / 64, NHEAD, 2);
  flash_attn_mfma<<<ga, blk, 0, stream>>>(qb, kb_, vbT, ctx);

  // 3: attn_out = ctx @ Wo + bo
  dim3 g768(DMODEL / 64, MROWS / 128);
  mfma_gemm_kernel<64><<<g768, blk, 0, stream>>>(ctx, wot, bo, ao, DMODEL, DMODEL, 0, 0);

  // 4: x1 = LN(src + attn_out)
  add_ln_kernel<<<dim3(MROWS), blk, 0, stream>>>(src, ao, ln1w, ln1b, x1, 0, 1, 1);

  // 5: ff = relu(x1 @ W1 + b1)
  dim3 gF1(DFF_K / 128, MROWS / 128);
  mfma_gemm_kernel<128><<<gF1, blk, 0, stream>>>(x1, w1t, b1, ff, DMODEL, DFF_K, 1, 0);

  // 6: y2 = ff @ W2 + b2
  mfma_gemm_kernel<64><<<g768, blk, 0, stream>>>(ff, w2t, b2, y2, DFF_K, DMODEL, 0, 0);

  // 7: out = LN(x1 + y2)
  add_ln_kernel<<<dim3(MROWS), blk, 0, stream>>>(x1, y2, ln2w, ln2b, (float*)d_out, 1, 1, 0);
}

// Round 6
// 353.569 us; speedup vs baseline: 13.9521x; 1.1163x over previous
//
#include <hip/hip_runtime.h>
#include <hip/hip_bf16.h>

#define S_LEN 2048
#define DMODEL 768
#define NHEAD 12
#define DKH 64
#define DFF_K 3072
#define MROWS 4096   // B*S

typedef __attribute__((ext_vector_type(8))) short bf16x8;
typedef __attribute__((ext_vector_type(8))) unsigned short us8;
typedef __attribute__((ext_vector_type(4))) float f32x4;

__device__ __forceinline__ float bfu2f(unsigned short u) {
  return __uint_as_float(((unsigned int)u) << 16);
}
__device__ __forceinline__ unsigned short f2bfu(float f) {
  __hip_bfloat16 h = __float2bfloat16(f);
  return *reinterpret_cast<unsigned short*>(&h);
}

// ---------------------------------------------------------------------------
// fp32 -> bf16 elementwise convert
// ---------------------------------------------------------------------------
__global__ __launch_bounds__(256) void convert_kernel(
    const float* __restrict__ in, unsigned short* __restrict__ out, int n4)
{
  const int i = blockIdx.x * 256 + threadIdx.x;
  if (i < n4) {
    float4 v = *(const float4*)(in + (size_t)i * 4);
    ushort4 o;
    o.x = f2bfu(v.x); o.y = f2bfu(v.y); o.z = f2bfu(v.z); o.w = f2bfu(v.w);
    *(ushort4*)(out + (size_t)i * 4) = o;
  }
}

// ---------------------------------------------------------------------------
// fp32 [R][C] -> bf16 [C][R] transpose-convert (generic, head or flat).
// ---------------------------------------------------------------------------
__device__ __forceinline__ void transpose_conv_body(
    const float* in, unsigned short* out, int R, int Ctot, int head,
    int bx, int by, int tid)
{
  __shared__ float t[64][68];
  const int r0 = bx * 64;
  const int c0 = by * 64;
  const float* ib;
  int ld;
  if (head) { ib = in + (size_t)by * R * 64; ld = 64; }
  else      { ib = in + c0;                  ld = Ctot; }
  const int lr = tid >> 4;
  const int lc = (tid & 15) << 2;

#pragma unroll
  for (int rr = 0; rr < 4; ++rr) {
    const int row = rr * 16 + lr;
    float4 v = *(const float4*)(ib + (size_t)(r0 + row) * ld + lc);
    t[row][lc + 0] = v.x; t[row][lc + 1] = v.y;
    t[row][lc + 2] = v.z; t[row][lc + 3] = v.w;
  }
  __syncthreads();
#pragma unroll
  for (int rr = 0; rr < 4; ++rr) {
    const int oc = rr * 16 + lr;
    ushort4 o;
    o.x = f2bfu(t[lc + 0][oc]); o.y = f2bfu(t[lc + 1][oc]);
    o.z = f2bfu(t[lc + 2][oc]); o.w = f2bfu(t[lc + 3][oc]);
    *(ushort4*)(out + (size_t)(c0 + oc) * R + r0 + lc) = o;
  }
}

__global__ __launch_bounds__(256) void transpose_conv_kernel(
    const float* __restrict__ in, unsigned short* __restrict__ out,
    int R, int Ctot, int head)
{
  transpose_conv_body(in, out, R, Ctot, head, blockIdx.x, blockIdx.y, threadIdx.x);
}

// fused Wq/Wk/Wv/Wo transpose: z selects tensor; z<3 head-mode
__global__ __launch_bounds__(256) void transpose_conv4_kernel(
    const float* __restrict__ i0, const float* __restrict__ i1,
    const float* __restrict__ i2, const float* __restrict__ i3,
    unsigned short* __restrict__ o0, unsigned short* __restrict__ o1,
    unsigned short* __restrict__ o2, unsigned short* __restrict__ o3)
{
  const int z = blockIdx.z;
  const float* in = (z == 0) ? i0 : (z == 1) ? i1 : (z == 2) ? i2 : i3;
  unsigned short* out = (z == 0) ? o0 : (z == 1) ? o1 : (z == 2) ? o2 : o3;
  transpose_conv_body(in, out, DMODEL, DMODEL, (z < 3) ? 1 : 0,
                      blockIdx.x, blockIdx.y, threadIdx.x);
}

// ---------------------------------------------------------------------------
// MFMA bf16 GEMM: C = act(A[M x K] @ BT[N x K]^T + bias). BM=128.
// ---------------------------------------------------------------------------
template<int BN>
__global__ __launch_bounds__(256) void mfma_gemm_kernel(
    const unsigned short* __restrict__ A,
    const unsigned short* __restrict__ BT,
    const float* __restrict__ bias,
    unsigned short* __restrict__ C,
    int K, int N, int relu, int store_vt)
{
  constexpr int WN = (BN == 128) ? 64 : 32;
  constexpr int NJ = WN / 16;
  __shared__ unsigned short As[128][40];
  __shared__ unsigned short Bs[BN][40];

  const int tid  = threadIdx.x;
  const int wid  = tid >> 6;
  const int lane = tid & 63;
  const int ml   = lane & 15;
  const int quad = lane >> 4;
  const int wm   = (wid & 1) * 64;
  const int wn   = (wid >> 1) * WN;
  const int row0 = blockIdx.y * 128;
  const int col0 = blockIdx.x * BN;

  const int sr = tid >> 2;
  const int sk = (tid & 3) << 3;

  f32x4 acc[4][NJ];
#pragma unroll
  for (int i = 0; i < 4; ++i)
#pragma unroll
    for (int j = 0; j < NJ; ++j)
#pragma unroll
      for (int r = 0; r < 4; ++r) acc[i][j][r] = 0.f;

  for (int k0 = 0; k0 < K; k0 += 32) {
    us8 a0 = *(const us8*)(A + (size_t)(row0 + sr) * K + k0 + sk);
    us8 a1 = *(const us8*)(A + (size_t)(row0 + sr + 64) * K + k0 + sk);
    us8 b0 = *(const us8*)(BT + (size_t)(col0 + sr) * K + k0 + sk);
    *(us8*)&As[sr][sk]      = a0;
    *(us8*)&As[sr + 64][sk] = a1;
    *(us8*)&Bs[sr][sk]      = b0;
    if (BN == 128) {
      us8 b1 = *(const us8*)(BT + (size_t)(col0 + sr + 64) * K + k0 + sk);
      *(us8*)&Bs[sr + 64][sk] = b1;
    }
    __syncthreads();

    bf16x8 af[4], bfr[NJ];
#pragma unroll
    for (int i = 0; i < 4; ++i)
      af[i] = *(const bf16x8*)&As[wm + i * 16 + ml][quad << 3];
#pragma unroll
    for (int j = 0; j < NJ; ++j)
      bfr[j] = *(const bf16x8*)&Bs[wn + j * 16 + ml][quad << 3];
#pragma unroll
    for (int i = 0; i < 4; ++i)
#pragma unroll
      for (int j = 0; j < NJ; ++j)
        acc[i][j] = __builtin_amdgcn_mfma_f32_16x16x32_bf16(
            af[i], bfr[j], acc[i][j], 0, 0, 0);
    __syncthreads();
  }

#pragma unroll
  for (int j = 0; j < NJ; ++j) {
    const int col = col0 + wn + j * 16 + ml;
    const float bb = bias[col];
#pragma unroll
    for (int i = 0; i < 4; ++i) {
      const int r0g = row0 + wm + i * 16 + (quad << 2);
      if (store_vt) {
        const int bb_ = r0g >> 11, s = r0g & 2047;
        const int hh = col >> 6, dd = col & 63;
        ushort4 o;
        o.x = f2bfu(acc[i][j][0] + bb); o.y = f2bfu(acc[i][j][1] + bb);
        o.z = f2bfu(acc[i][j][2] + bb); o.w = f2bfu(acc[i][j][3] + bb);
        *(ushort4*)(C + ((size_t)((bb_ * NHEAD + hh) * DKH + dd)) * S_LEN + s) = o;
      } else {
#pragma unroll
        for (int r = 0; r < 4; ++r) {
          float v = acc[i][j][r] + bb;
          if (relu) v = fmaxf(v, 0.f);
          C[(size_t)(r0g + r) * N + col] = f2bfu(v);
        }
      }
    }
  }
}

// fused QKV projection: z=0 -> Q, z=1 -> K, z=2 -> V (VT store). BN=64.
__global__ __launch_bounds__(256) void qkv_gemm_kernel(
    const unsigned short* __restrict__ A,
    const unsigned short* __restrict__ W0, const unsigned short* __restrict__ W1,
    const unsigned short* __restrict__ W2,
    const float* __restrict__ bq, const float* __restrict__ bk,
    const float* __restrict__ bv,
    unsigned short* __restrict__ C0, unsigned short* __restrict__ C1,
    unsigned short* __restrict__ C2)
{
  __shared__ unsigned short As[128][40];
  __shared__ unsigned short Bs[64][40];
  const int z = blockIdx.z;
  const unsigned short* BT = (z == 0) ? W0 : (z == 1) ? W1 : W2;
  const float* bias = (z == 0) ? bq : (z == 1) ? bk : bv;
  unsigned short* C = (z == 0) ? C0 : (z == 1) ? C1 : C2;
  const int K = DMODEL, N = DMODEL;

  const int tid  = threadIdx.x;
  const int wid  = tid >> 6;
  const int lane = tid & 63;
  const int ml   = lane & 15;
  const int quad = lane >> 4;
  const int wm   = (wid & 1) * 64;
  const int wn   = (wid >> 1) * 32;
  const int row0 = blockIdx.y * 128;
  const int col0 = blockIdx.x * 64;
  const int sr = tid >> 2;
  const int sk = (tid & 3) << 3;

  f32x4 acc[4][2];
#pragma unroll
  for (int i = 0; i < 4; ++i)
#pragma unroll
    for (int j = 0; j < 2; ++j)
#pragma unroll
      for (int r = 0; r < 4; ++r) acc[i][j][r] = 0.f;

  for (int k0 = 0; k0 < K; k0 += 32) {
    us8 a0 = *(const us8*)(A + (size_t)(row0 + sr) * K + k0 + sk);
    us8 a1 = *(const us8*)(A + (size_t)(row0 + sr + 64) * K + k0 + sk);
    us8 b0 = *(const us8*)(BT + (size_t)(col0 + sr) * K + k0 + sk);
    *(us8*)&As[sr][sk]      = a0;
    *(us8*)&As[sr + 64][sk] = a1;
    *(us8*)&Bs[sr][sk]      = b0;
    __syncthreads();
    bf16x8 af[4], bfr[2];
#pragma unroll
    for (int i = 0; i < 4; ++i)
      af[i] = *(const bf16x8*)&As[wm + i * 16 + ml][quad << 3];
#pragma unroll
    for (int j = 0; j < 2; ++j)
      bfr[j] = *(const bf16x8*)&Bs[wn + j * 16 + ml][quad << 3];
#pragma unroll
    for (int i = 0; i < 4; ++i)
#pragma unroll
      for (int j = 0; j < 2; ++j)
        acc[i][j] = __builtin_amdgcn_mfma_f32_16x16x32_bf16(
            af[i], bfr[j], acc[i][j], 0, 0, 0);
    __syncthreads();
  }

#pragma unroll
  for (int j = 0; j < 2; ++j) {
    const int col = col0 + wn + j * 16 + ml;
    const float bb = bias[col];
#pragma unroll
    for (int i = 0; i < 4; ++i) {
      const int r0g = row0 + wm + i * 16 + (quad << 2);
      if (z == 2) {
        const int bb_ = r0g >> 11, s = r0g & 2047;
        const int hh = col >> 6, dd = col & 63;
        ushort4 o;
        o.x = f2bfu(acc[i][j][0] + bb); o.y = f2bfu(acc[i][j][1] + bb);
        o.z = f2bfu(acc[i][j][2] + bb); o.w = f2bfu(acc[i][j][3] + bb);
        *(ushort4*)(C + ((size_t)((bb_ * NHEAD + hh) * DKH + dd)) * S_LEN + s) = o;
      } else {
#pragma unroll
        for (int r = 0; r < 4; ++r)
          C[(size_t)(r0g + r) * N + col] = f2bfu(acc[i][j][r] + bb);
      }
    }
  }
}

// ---------------------------------------------------------------------------
// MFMA flash attention, S-TRANSPOSED formulation.
// Block = 64 q-rows of one (b,h); wave w owns q-rows w*16..w*16+15.
// S^T = K @ Q^T  (mfma(kf, qf): D col=ml=q, row=quad*4+r=t)
//   -> softmax stats are IN-LANE over 16 t-values + 2 shuffles (xor 16,32);
//      alpha/m/l are per-lane scalars.
// P^T written to per-wave LDS as [q][t] with b64 packs (4 consecutive t);
// PV: O^T = V^T @ P^T^T via mfma(vf, pf): D col=q, row=d. V^T tile comes
// from the VT[b,h,d,s] layout produced by the V projection.
// LDS 36.9 KB -> 4 blocks/CU.
// ---------------------------------------------------------------------------
#define FATS 72
__global__ __launch_bounds__(256) void flash_attn_mfma(
    const unsigned short* __restrict__ Q,
    const unsigned short* __restrict__ K,
    const unsigned short* __restrict__ VT,
    unsigned short* __restrict__ O)
{
  __shared__ unsigned short Qs[64][FATS];
  __shared__ unsigned short Ks[64][FATS];
  __shared__ unsigned short Vs[64][FATS];      // VT tile: [d][t_local]
  __shared__ unsigned short PsT[4][16][FATS];  // per-wave P^T: [q][t_local]

  const int tid  = threadIdx.x;
  const int wid  = tid >> 6;
  const int lane = tid & 63;
  const int ml   = lane & 15;
  const int quad = lane >> 4;
  const int b    = blockIdx.z, h = blockIdx.y;
  const int q0   = blockIdx.x * 64;

  const size_t qkbase = ((size_t)b * S_LEN) * DMODEL + (size_t)h * DKH;
  const size_t vtbase = ((size_t)(b * NHEAD + h)) * DKH * S_LEN;

  const int sr = tid >> 2;          // 0..63
  const int sc = (tid & 3) << 4;    // 0,16,32,48

  // ---- stage Q (natural [q][d]) ----
  {
    const unsigned short* qp = Q + qkbase + (size_t)(q0 + sr) * DMODEL + sc;
    *(us8*)&Qs[sr][sc]     = *(const us8*)qp;
    *(us8*)&Qs[sr][sc + 8] = *(const us8*)(qp + 8);
  }
  __syncthreads();

  bf16x8 qf[2];  // B-frag: Q[n=q=ml][k=d]
  qf[0] = *(const bf16x8*)&Qs[wid * 16 + ml][quad << 3];
  qf[1] = *(const bf16x8*)&Qs[wid * 16 + ml][32 + (quad << 3)];

  float m_run = -1e30f, l_run = 0.f;
  f32x4 oacc[4];
#pragma unroll
  for (int dt = 0; dt < 4; ++dt)
#pragma unroll
    for (int r = 0; r < 4; ++r) oacc[dt][r] = 0.f;

  for (int kt = 0; kt < S_LEN; kt += 64) {
    __syncthreads();   // prior tile's Ks/Vs readers done
    {
      const unsigned short* kp = K + qkbase + (size_t)(kt + sr) * DMODEL + sc;
      *(us8*)&Ks[sr][sc]     = *(const us8*)kp;
      *(us8*)&Ks[sr][sc + 8] = *(const us8*)(kp + 8);
      const unsigned short* vp = VT + vtbase + (size_t)sr * S_LEN + kt + sc;
      *(us8*)&Vs[sr][sc]     = *(const us8*)vp;
      *(us8*)&Vs[sr][sc + 8] = *(const us8*)(vp + 8);
    }
    __syncthreads();

    // ---- S^T tile: 4 m-tiles (t), col = q = ml ----
    f32x4 sacc[4];
#pragma unroll
    for (int mt = 0; mt < 4; ++mt)
#pragma unroll
      for (int r = 0; r < 4; ++r) sacc[mt][r] = 0.f;
#pragma unroll
    for (int mt = 0; mt < 4; ++mt) {
      bf16x8 kf0 = *(const bf16x8*)&Ks[mt * 16 + ml][quad << 3];
      bf16x8 kf1 = *(const bf16x8*)&Ks[mt * 16 + ml][32 + (quad << 3)];
      sacc[mt] = __builtin_amdgcn_mfma_f32_16x16x32_bf16(kf0, qf[0], sacc[mt], 0, 0, 0);
      sacc[mt] = __builtin_amdgcn_mfma_f32_16x16x32_bf16(kf1, qf[1], sacc[mt], 0, 0, 0);
    }

    // ---- online softmax: lane owns q = ml; 16 t-values in-register ----
    float mt_ = fmaxf(fmaxf(fmaxf(sacc[0][0], sacc[0][1]), fmaxf(sacc[0][2], sacc[0][3])),
                      fmaxf(fmaxf(sacc[1][0], sacc[1][1]), fmaxf(sacc[1][2], sacc[1][3])));
    mt_ = fmaxf(mt_,
          fmaxf(fmaxf(fmaxf(sacc[2][0], sacc[2][1]), fmaxf(sacc[2][2], sacc[2][3])),
                fmaxf(fmaxf(sacc[3][0], sacc[3][1]), fmaxf(sacc[3][2], sacc[3][3]))));
    mt_ *= 0.125f;
    mt_ = fmaxf(mt_, __shfl_xor(mt_, 16));
    mt_ = fmaxf(mt_, __shfl_xor(mt_, 32));
    const float m_new = fmaxf(m_run, mt_);
    const float alpha = __expf(m_run - m_new);
    float p[4][4];
    float rs = 0.f;
#pragma unroll
    for (int mt2 = 0; mt2 < 4; ++mt2)
#pragma unroll
      for (int r = 0; r < 4; ++r) {
        const float e = __expf(sacc[mt2][r] * 0.125f - m_new);
        p[mt2][r] = e;
        rs += e;
      }
    rs += __shfl_xor(rs, 16);
    rs += __shfl_xor(rs, 32);
    l_run = l_run * alpha + rs;
    m_run = m_new;
#pragma unroll
    for (int dt = 0; dt < 4; ++dt)
#pragma unroll
      for (int r = 0; r < 4; ++r) oacc[dt][r] *= alpha;

    // ---- P^T -> per-wave LDS: PsT[q=ml][t=16mt+4quad+r], b64 packs ----
#pragma unroll
    for (int mt2 = 0; mt2 < 4; ++mt2) {
      ushort4 o;
      o.x = f2bfu(p[mt2][0]); o.y = f2bfu(p[mt2][1]);
      o.z = f2bfu(p[mt2][2]); o.w = f2bfu(p[mt2][3]);
      *(ushort4*)&PsT[wid][ml][mt2 * 16 + (quad << 2)] = o;
    }
    bf16x8 pf0 = *(const bf16x8*)&PsT[wid][ml][quad << 3];
    bf16x8 pf1 = *(const bf16x8*)&PsT[wid][ml][32 + (quad << 3)];

    // ---- PV: O^T += V^T @ P^T^T ----
#pragma unroll
    for (int dt = 0; dt < 4; ++dt) {
      bf16x8 vf0 = *(const bf16x8*)&Vs[dt * 16 + ml][quad << 3];
      bf16x8 vf1 = *(const bf16x8*)&Vs[dt * 16 + ml][32 + (quad << 3)];
      oacc[dt] = __builtin_amdgcn_mfma_f32_16x16x32_bf16(vf0, pf0, oacc[dt], 0, 0, 0);
      oacc[dt] = __builtin_amdgcn_mfma_f32_16x16x32_bf16(vf1, pf1, oacc[dt], 0, 0, 0);
    }
  }

  // ---- epilogue: lane q = q0+wid*16+ml; d = dt*16+quad*4+r ----
  const float inv = 1.f / l_run;
  const int qrow = q0 + wid * 16 + ml;
#pragma unroll
  for (int dt = 0; dt < 4; ++dt)
#pragma unroll
    for (int r = 0; r < 4; ++r)
      O[qkbase + (size_t)qrow * DMODEL + dt * 16 + (quad << 2) + r] =
          f2bfu(oacc[dt][r] * inv);
}

// ---------------------------------------------------------------------------
// out = LayerNorm(X + Y) * w + b; dtype flags (1 = bf16)
// ---------------------------------------------------------------------------
__global__ __launch_bounds__(256) void add_ln_kernel(
    const void* __restrict__ X, const void* __restrict__ Y,
    const float* __restrict__ w, const float* __restrict__ bvec,
    void* __restrict__ out, int xbf, int ybf, int obf)
{
  __shared__ float buf[DMODEL];
  __shared__ float rbuf[8];
  const int tid  = threadIdx.x;
  const int lane = tid & 63, wv = tid >> 6;
  const size_t base = (size_t)blockIdx.x * DMODEL;

  float s = 0.f, s2 = 0.f;
#pragma unroll
  for (int j = tid; j < DMODEL; j += 256) {
    float xv = xbf ? bfu2f(((const unsigned short*)X)[base + j])
                   : ((const float*)X)[base + j];
    float yv = ybf ? bfu2f(((const unsigned short*)Y)[base + j])
                   : ((const float*)Y)[base + j];
    float v = xv + yv;
    buf[j] = v; s += v; s2 += v * v;
  }
#pragma unroll
  for (int o = 32; o; o >>= 1) { s += __shfl_xor(s, o); s2 += __shfl_xor(s2, o); }
  if (lane == 0) { rbuf[wv] = s; rbuf[4 + wv] = s2; }
  __syncthreads();
  const float S  = rbuf[0] + rbuf[1] + rbuf[2] + rbuf[3];
  const float S2 = rbuf[4] + rbuf[5] + rbuf[6] + rbuf[7];
  const float mean = S * (1.f / (float)DMODEL);
  const float var  = S2 * (1.f / (float)DMODEL) - mean * mean;
  const float rstd = rsqrtf(var + 1e-5f);
#pragma unroll
  for (int j = tid; j < DMODEL; j += 256) {
    float v = (buf[j] - mean) * rstd * w[j] + bvec[j];
    if (obf) ((unsigned short*)out)[base + j] = f2bfu(v);
    else     ((float*)out)[base + j] = v;
  }
}

// ---------------------------------------------------------------------------
extern "C" void kernel_launch(void* const* d_in, const int* in_sizes, int n_in,
                              void* d_out, int out_size, void* d_ws, size_t ws_size,
                              hipStream_t stream) {
  const float* src  = (const float*)d_in[0];
  const float* Wq   = (const float*)d_in[1];
  const float* bq   = (const float*)d_in[2];
  const float* Wk   = (const float*)d_in[3];
  const float* bk   = (const float*)d_in[4];
  const float* Wv   = (const float*)d_in[5];
  const float* bv   = (const float*)d_in[6];
  const float* Wo   = (const float*)d_in[7];
  const float* bo   = (const float*)d_in[8];
  const float* ln1w = (const float*)d_in[9];
  const float* ln1b = (const float*)d_in[10];
  const float* W1   = (const float*)d_in[11];
  const float* b1   = (const float*)d_in[12];
  const float* W2   = (const float*)d_in[13];
  const float* b2   = (const float*)d_in[14];
  const float* ln2w = (const float*)d_in[15];
  const float* ln2b = (const float*)d_in[16];
  (void)ws_size; (void)in_sizes; (void)n_in; (void)out_size;

  unsigned short* p = (unsigned short*)d_ws;
  const size_t SEG = (size_t)MROWS * DMODEL;
  unsigned short* srcb = p; p += SEG;
  unsigned short* qb   = p; p += SEG;
  unsigned short* kb_  = p; p += SEG;
  unsigned short* vbT  = p; p += SEG;          // [b,h,64,2048]
  unsigned short* ctx  = p; p += SEG;
  unsigned short* ff   = p; p += (size_t)MROWS * DFF_K;
  unsigned short* wqt  = p; p += (size_t)DMODEL * DMODEL;
  unsigned short* wkt  = p; p += (size_t)DMODEL * DMODEL;
  unsigned short* wvt  = p; p += (size_t)DMODEL * DMODEL;
  unsigned short* wot  = p; p += (size_t)DMODEL * DMODEL;
  unsigned short* w1t  = p; p += (size_t)DMODEL * DFF_K;
  unsigned short* w2t  = p; p += (size_t)DMODEL * DFF_K;
  unsigned short* ao = qb;
  unsigned short* x1 = kb_;
  unsigned short* y2 = vbT;

  dim3 blk(256);

  // 0: conversions
  convert_kernel<<<dim3(SEG / 1024), blk, 0, stream>>>(src, srcb, (int)(SEG / 4));
  transpose_conv4_kernel<<<dim3(12, 12, 4), blk, 0, stream>>>(
      Wq, Wk, Wv, Wo, wqt, wkt, wvt, wot);
  transpose_conv_kernel<<<dim3(12, 48), blk, 0, stream>>>(W1, w1t, DMODEL, DFF_K, 0);
  transpose_conv_kernel<<<dim3(48, 12), blk, 0, stream>>>(W2, w2t, DFF_K, DMODEL, 0);

  // 1: fused QKV projections (V written transposed per head)
  dim3 gqkv(DMODEL / 64, MROWS / 128, 3);
  qkv_gemm_kernel<<<gqkv, blk, 0, stream>>>(srcb, wqt, wkt, wvt, bq, bk, bv,
                                            qb, kb_, vbT);

  // 2: MFMA flash attention (S^T form) -> ctx
  dim3 ga(S_LEN / 64, NHEAD, 2);
  flash_attn_mfma<<<ga, blk, 0, stream>>>(qb, kb_, vbT, ctx);

  // 3: attn_out = ctx @ Wo + bo
  dim3 g768(DMODEL / 64, MROWS / 128);
  mfma_gemm_kernel<64><<<g768, blk, 0, stream>>>(ctx, wot, bo, ao, DMODEL, DMODEL, 0, 0);

  // 4: x1 = LN(srcb + attn_out)   (bf16 residual read)
  add_ln_kernel<<<dim3(MROWS), blk, 0, stream>>>(srcb, ao, ln1w, ln1b, x1, 1, 1, 1);

  // 5: ff = relu(x1 @ W1 + b1)
  dim3 gF1(DFF_K / 128, MROWS / 128);
  mfma_gemm_kernel<128><<<gF1, blk, 0, stream>>>(x1, w1t, b1, ff, DMODEL, DFF_K, 1, 0);

  // 6: y2 = ff @ W2 + b2
  mfma_gemm_kernel<64><<<g768, blk, 0, stream>>>(ff, w2t, b2, y2, DFF_K, DMODEL, 0, 0);

  // 7: out = LN(x1 + y2)
  add_ln_kernel<<<dim3(MROWS), blk, 0, stream>>>(x1, y2, ln2w, ln2b, (float*)d_out, 1, 1, 0);
}

// Round 7
// 321.703 us; speedup vs baseline: 15.3341x; 1.0991x over previous
//
#include <hip/hip_runtime.h>
#include <hip/hip_bf16.h>

#define S_LEN 2048
#define DMODEL 768
#define NHEAD 12
#define DKH 64
#define DFF_K 3072
#define MROWS 4096   // B*S

typedef __attribute__((ext_vector_type(8))) short bf16x8;
typedef __attribute__((ext_vector_type(8))) unsigned short us8;
typedef __attribute__((ext_vector_type(4))) float f32x4;

__device__ __forceinline__ float bfu2f(unsigned short u) {
  return __uint_as_float(((unsigned int)u) << 16);
}
__device__ __forceinline__ unsigned short f2bfu(float f) {
  __hip_bfloat16 h = __float2bfloat16(f);
  return *reinterpret_cast<unsigned short*>(&h);
}

// ---------------------------------------------------------------------------
// fp32 -> bf16 elementwise convert
// ---------------------------------------------------------------------------
__global__ __launch_bounds__(256) void convert_kernel(
    const float* __restrict__ in, unsigned short* __restrict__ out, int n4)
{
  const int i = blockIdx.x * 256 + threadIdx.x;
  if (i < n4) {
    float4 v = *(const float4*)(in + (size_t)i * 4);
    ushort4 o;
    o.x = f2bfu(v.x); o.y = f2bfu(v.y); o.z = f2bfu(v.z); o.w = f2bfu(v.w);
    *(ushort4*)(out + (size_t)i * 4) = o;
  }
}

// ---------------------------------------------------------------------------
// fp32 [R][C] -> bf16 [C][R] transpose-convert (generic, head or flat).
// ---------------------------------------------------------------------------
__device__ __forceinline__ void transpose_conv_body(
    const float* in, unsigned short* out, int R, int Ctot, int head,
    int bx, int by, int tid)
{
  __shared__ float t[64][68];
  const int r0 = bx * 64;
  const int c0 = by * 64;
  const float* ib;
  int ld;
  if (head) { ib = in + (size_t)by * R * 64; ld = 64; }
  else      { ib = in + c0;                  ld = Ctot; }
  const int lr = tid >> 4;
  const int lc = (tid & 15) << 2;

#pragma unroll
  for (int rr = 0; rr < 4; ++rr) {
    const int row = rr * 16 + lr;
    float4 v = *(const float4*)(ib + (size_t)(r0 + row) * ld + lc);
    t[row][lc + 0] = v.x; t[row][lc + 1] = v.y;
    t[row][lc + 2] = v.z; t[row][lc + 3] = v.w;
  }
  __syncthreads();
#pragma unroll
  for (int rr = 0; rr < 4; ++rr) {
    const int oc = rr * 16 + lr;
    ushort4 o;
    o.x = f2bfu(t[lc + 0][oc]); o.y = f2bfu(t[lc + 1][oc]);
    o.z = f2bfu(t[lc + 2][oc]); o.w = f2bfu(t[lc + 3][oc]);
    *(ushort4*)(out + (size_t)(c0 + oc) * R + r0 + lc) = o;
  }
}

__global__ __launch_bounds__(256) void transpose_conv_kernel(
    const float* __restrict__ in, unsigned short* __restrict__ out,
    int R, int Ctot, int head)
{
  transpose_conv_body(in, out, R, Ctot, head, blockIdx.x, blockIdx.y, threadIdx.x);
}

// fused Wq/Wk/Wv/Wo transpose: z selects tensor; z<3 head-mode
__global__ __launch_bounds__(256) void transpose_conv4_kernel(
    const float* __restrict__ i0, const float* __restrict__ i1,
    const float* __restrict__ i2, const float* __restrict__ i3,
    unsigned short* __restrict__ o0, unsigned short* __restrict__ o1,
    unsigned short* __restrict__ o2, unsigned short* __restrict__ o3)
{
  const int z = blockIdx.z;
  const float* in = (z == 0) ? i0 : (z == 1) ? i1 : (z == 2) ? i2 : i3;
  unsigned short* out = (z == 0) ? o0 : (z == 1) ? o1 : (z == 2) ? o2 : o3;
  transpose_conv_body(in, out, DMODEL, DMODEL, (z < 3) ? 1 : 0,
                      blockIdx.x, blockIdx.y, threadIdx.x);
}

// ---------------------------------------------------------------------------
// MFMA bf16 GEMM: C = act(A[M x K] @ BT[N x K]^T + bias). BM=128.
// Grid: x = M row-block (FASTEST -> all col-blocks of a row-block land on the
// same XCD under round-robin placement, A-tile fetched once per XCD),
// y = N col-block, z = K-split (partial z writes C + z*out_stride; bias only
// applied by z==0; summed downstream).
// ---------------------------------------------------------------------------
template<int BN>
__global__ __launch_bounds__(256) void mfma_gemm_kernel(
    const unsigned short* __restrict__ A,
    const unsigned short* __restrict__ BT,
    const float* __restrict__ bias,
    unsigned short* __restrict__ C,
    int K, int N, int relu, int klen, size_t out_stride)
{
  constexpr int WN = (BN == 128) ? 64 : 32;
  constexpr int NJ = WN / 16;
  __shared__ unsigned short As[128][40];
  __shared__ unsigned short Bs[BN][40];

  const int tid  = threadIdx.x;
  const int wid  = tid >> 6;
  const int lane = tid & 63;
  const int ml   = lane & 15;
  const int quad = lane >> 4;
  const int wm   = (wid & 1) * 64;
  const int wn   = (wid >> 1) * WN;
  const int row0 = blockIdx.x * 128;
  const int col0 = blockIdx.y * BN;
  const int zed  = blockIdx.z;
  const int kb0  = zed * klen;

  const int sr = tid >> 2;
  const int sk = (tid & 3) << 3;

  f32x4 acc[4][NJ];
#pragma unroll
  for (int i = 0; i < 4; ++i)
#pragma unroll
    for (int j = 0; j < NJ; ++j)
#pragma unroll
      for (int r = 0; r < 4; ++r) acc[i][j][r] = 0.f;

  for (int k0 = kb0; k0 < kb0 + klen; k0 += 32) {
    us8 a0 = *(const us8*)(A + (size_t)(row0 + sr) * K + k0 + sk);
    us8 a1 = *(const us8*)(A + (size_t)(row0 + sr + 64) * K + k0 + sk);
    us8 b0 = *(const us8*)(BT + (size_t)(col0 + sr) * K + k0 + sk);
    *(us8*)&As[sr][sk]      = a0;
    *(us8*)&As[sr + 64][sk] = a1;
    *(us8*)&Bs[sr][sk]      = b0;
    if (BN == 128) {
      us8 b1 = *(const us8*)(BT + (size_t)(col0 + sr + 64) * K + k0 + sk);
      *(us8*)&Bs[sr + 64][sk] = b1;
    }
    __syncthreads();

    bf16x8 af[4], bfr[NJ];
#pragma unroll
    for (int i = 0; i < 4; ++i)
      af[i] = *(const bf16x8*)&As[wm + i * 16 + ml][quad << 3];
#pragma unroll
    for (int j = 0; j < NJ; ++j)
      bfr[j] = *(const bf16x8*)&Bs[wn + j * 16 + ml][quad << 3];
#pragma unroll
    for (int i = 0; i < 4; ++i)
#pragma unroll
      for (int j = 0; j < NJ; ++j)
        acc[i][j] = __builtin_amdgcn_mfma_f32_16x16x32_bf16(
            af[i], bfr[j], acc[i][j], 0, 0, 0);
    __syncthreads();
  }

  unsigned short* Cz = C + (size_t)zed * out_stride;
#pragma unroll
  for (int j = 0; j < NJ; ++j) {
    const int col = col0 + wn + j * 16 + ml;
    const float bb = (zed == 0) ? bias[col] : 0.f;
#pragma unroll
    for (int i = 0; i < 4; ++i) {
      const int r0g = row0 + wm + i * 16 + (quad << 2);
#pragma unroll
      for (int r = 0; r < 4; ++r) {
        float v = acc[i][j][r] + bb;
        if (relu) v = fmaxf(v, 0.f);
        Cz[(size_t)(r0g + r) * N + col] = f2bfu(v);
      }
    }
  }
}

// fused QKV projection: z=0 -> Q, z=1 -> K, z=2 -> V (VT store). BN=64.
// Grid: x = row-block (fastest), y = col-block, z = tensor.
__global__ __launch_bounds__(256) void qkv_gemm_kernel(
    const unsigned short* __restrict__ A,
    const unsigned short* __restrict__ W0, const unsigned short* __restrict__ W1,
    const unsigned short* __restrict__ W2,
    const float* __restrict__ bq, const float* __restrict__ bk,
    const float* __restrict__ bv,
    unsigned short* __restrict__ C0, unsigned short* __restrict__ C1,
    unsigned short* __restrict__ C2)
{
  __shared__ unsigned short As[128][40];
  __shared__ unsigned short Bs[64][40];
  const int z = blockIdx.z;
  const unsigned short* BT = (z == 0) ? W0 : (z == 1) ? W1 : W2;
  const float* bias = (z == 0) ? bq : (z == 1) ? bk : bv;
  unsigned short* C = (z == 0) ? C0 : (z == 1) ? C1 : C2;
  const int K = DMODEL, N = DMODEL;

  const int tid  = threadIdx.x;
  const int wid  = tid >> 6;
  const int lane = tid & 63;
  const int ml   = lane & 15;
  const int quad = lane >> 4;
  const int wm   = (wid & 1) * 64;
  const int wn   = (wid >> 1) * 32;
  const int row0 = blockIdx.x * 128;
  const int col0 = blockIdx.y * 64;
  const int sr = tid >> 2;
  const int sk = (tid & 3) << 3;

  f32x4 acc[4][2];
#pragma unroll
  for (int i = 0; i < 4; ++i)
#pragma unroll
    for (int j = 0; j < 2; ++j)
#pragma unroll
      for (int r = 0; r < 4; ++r) acc[i][j][r] = 0.f;

  for (int k0 = 0; k0 < K; k0 += 32) {
    us8 a0 = *(const us8*)(A + (size_t)(row0 + sr) * K + k0 + sk);
    us8 a1 = *(const us8*)(A + (size_t)(row0 + sr + 64) * K + k0 + sk);
    us8 b0 = *(const us8*)(BT + (size_t)(col0 + sr) * K + k0 + sk);
    *(us8*)&As[sr][sk]      = a0;
    *(us8*)&As[sr + 64][sk] = a1;
    *(us8*)&Bs[sr][sk]      = b0;
    __syncthreads();
    bf16x8 af[4], bfr[2];
#pragma unroll
    for (int i = 0; i < 4; ++i)
      af[i] = *(const bf16x8*)&As[wm + i * 16 + ml][quad << 3];
#pragma unroll
    for (int j = 0; j < 2; ++j)
      bfr[j] = *(const bf16x8*)&Bs[wn + j * 16 + ml][quad << 3];
#pragma unroll
    for (int i = 0; i < 4; ++i)
#pragma unroll
      for (int j = 0; j < 2; ++j)
        acc[i][j] = __builtin_amdgcn_mfma_f32_16x16x32_bf16(
            af[i], bfr[j], acc[i][j], 0, 0, 0);
    __syncthreads();
  }

#pragma unroll
  for (int j = 0; j < 2; ++j) {
    const int col = col0 + wn + j * 16 + ml;
    const float bb = bias[col];
#pragma unroll
    for (int i = 0; i < 4; ++i) {
      const int r0g = row0 + wm + i * 16 + (quad << 2);
      if (z == 2) {
        const int bb_ = r0g >> 11, s = r0g & 2047;
        const int hh = col >> 6, dd = col & 63;
        ushort4 o;
        o.x = f2bfu(acc[i][j][0] + bb); o.y = f2bfu(acc[i][j][1] + bb);
        o.z = f2bfu(acc[i][j][2] + bb); o.w = f2bfu(acc[i][j][3] + bb);
        *(ushort4*)(C + ((size_t)((bb_ * NHEAD + hh) * DKH + dd)) * S_LEN + s) = o;
      } else {
#pragma unroll
        for (int r = 0; r < 4; ++r)
          C[(size_t)(r0g + r) * N + col] = f2bfu(acc[i][j][r] + bb);
      }
    }
  }
}

// ---------------------------------------------------------------------------
// MFMA flash attention, S-TRANSPOSED formulation.
// Grid: x = head (fastest), y = batch, z = q-tile  -> all q-tiles of one
// (b,h) land on the same XCD (K/V L2 reuse).
// ---------------------------------------------------------------------------
#define FATS 72
__global__ __launch_bounds__(256) void flash_attn_mfma(
    const unsigned short* __restrict__ Q,
    const unsigned short* __restrict__ K,
    const unsigned short* __restrict__ VT,
    unsigned short* __restrict__ O)
{
  __shared__ unsigned short Qs[64][FATS];
  __shared__ unsigned short Ks[64][FATS];
  __shared__ unsigned short Vs[64][FATS];      // VT tile: [d][t_local]
  __shared__ unsigned short PsT[4][16][FATS];  // per-wave P^T: [q][t_local]

  const int tid  = threadIdx.x;
  const int wid  = tid >> 6;
  const int lane = tid & 63;
  const int ml   = lane & 15;
  const int quad = lane >> 4;
  const int h    = blockIdx.x, b = blockIdx.y;
  const int q0   = blockIdx.z * 64;

  const size_t qkbase = ((size_t)b * S_LEN) * DMODEL + (size_t)h * DKH;
  const size_t vtbase = ((size_t)(b * NHEAD + h)) * DKH * S_LEN;

  const int sr = tid >> 2;          // 0..63
  const int sc = (tid & 3) << 4;    // 0,16,32,48

  // ---- stage Q (natural [q][d]) ----
  {
    const unsigned short* qp = Q + qkbase + (size_t)(q0 + sr) * DMODEL + sc;
    *(us8*)&Qs[sr][sc]     = *(const us8*)qp;
    *(us8*)&Qs[sr][sc + 8] = *(const us8*)(qp + 8);
  }
  __syncthreads();

  bf16x8 qf[2];  // B-frag: Q[n=q=ml][k=d]
  qf[0] = *(const bf16x8*)&Qs[wid * 16 + ml][quad << 3];
  qf[1] = *(const bf16x8*)&Qs[wid * 16 + ml][32 + (quad << 3)];

  float m_run = -1e30f, l_run = 0.f;
  f32x4 oacc[4];
#pragma unroll
  for (int dt = 0; dt < 4; ++dt)
#pragma unroll
    for (int r = 0; r < 4; ++r) oacc[dt][r] = 0.f;

  for (int kt = 0; kt < S_LEN; kt += 64) {
    __syncthreads();   // prior tile's Ks/Vs readers done
    {
      const unsigned short* kp = K + qkbase + (size_t)(kt + sr) * DMODEL + sc;
      *(us8*)&Ks[sr][sc]     = *(const us8*)kp;
      *(us8*)&Ks[sr][sc + 8] = *(const us8*)(kp + 8);
      const unsigned short* vp = VT + vtbase + (size_t)sr * S_LEN + kt + sc;
      *(us8*)&Vs[sr][sc]     = *(const us8*)vp;
      *(us8*)&Vs[sr][sc + 8] = *(const us8*)(vp + 8);
    }
    __syncthreads();

    // ---- S^T tile: 4 m-tiles (t), col = q = ml ----
    f32x4 sacc[4];
#pragma unroll
    for (int mt = 0; mt < 4; ++mt)
#pragma unroll
      for (int r = 0; r < 4; ++r) sacc[mt][r] = 0.f;
#pragma unroll
    for (int mt = 0; mt < 4; ++mt) {
      bf16x8 kf0 = *(const bf16x8*)&Ks[mt * 16 + ml][quad << 3];
      bf16x8 kf1 = *(const bf16x8*)&Ks[mt * 16 + ml][32 + (quad << 3)];
      sacc[mt] = __builtin_amdgcn_mfma_f32_16x16x32_bf16(kf0, qf[0], sacc[mt], 0, 0, 0);
      sacc[mt] = __builtin_amdgcn_mfma_f32_16x16x32_bf16(kf1, qf[1], sacc[mt], 0, 0, 0);
    }

    // ---- online softmax: lane owns q = ml; 16 t-values in-register ----
    float mt_ = fmaxf(fmaxf(fmaxf(sacc[0][0], sacc[0][1]), fmaxf(sacc[0][2], sacc[0][3])),
                      fmaxf(fmaxf(sacc[1][0], sacc[1][1]), fmaxf(sacc[1][2], sacc[1][3])));
    mt_ = fmaxf(mt_,
          fmaxf(fmaxf(fmaxf(sacc[2][0], sacc[2][1]), fmaxf(sacc[2][2], sacc[2][3])),
                fmaxf(fmaxf(sacc[3][0], sacc[3][1]), fmaxf(sacc[3][2], sacc[3][3]))));
    mt_ *= 0.125f;
    mt_ = fmaxf(mt_, __shfl_xor(mt_, 16));
    mt_ = fmaxf(mt_, __shfl_xor(mt_, 32));
    const float m_new = fmaxf(m_run, mt_);
    const float alpha = __expf(m_run - m_new);
    float p[4][4];
    float rs = 0.f;
#pragma unroll
    for (int mt2 = 0; mt2 < 4; ++mt2)
#pragma unroll
      for (int r = 0; r < 4; ++r) {
        const float e = __expf(sacc[mt2][r] * 0.125f - m_new);
        p[mt2][r] = e;
        rs += e;
      }
    rs += __shfl_xor(rs, 16);
    rs += __shfl_xor(rs, 32);
    l_run = l_run * alpha + rs;
    m_run = m_new;
#pragma unroll
    for (int dt = 0; dt < 4; ++dt)
#pragma unroll
      for (int r = 0; r < 4; ++r) oacc[dt][r] *= alpha;

    // ---- P^T -> per-wave LDS: PsT[q=ml][t=16mt+4quad+r], b64 packs ----
#pragma unroll
    for (int mt2 = 0; mt2 < 4; ++mt2) {
      ushort4 o;
      o.x = f2bfu(p[mt2][0]); o.y = f2bfu(p[mt2][1]);
      o.z = f2bfu(p[mt2][2]); o.w = f2bfu(p[mt2][3]);
      *(ushort4*)&PsT[wid][ml][mt2 * 16 + (quad << 2)] = o;
    }
    bf16x8 pf0 = *(const bf16x8*)&PsT[wid][ml][quad << 3];
    bf16x8 pf1 = *(const bf16x8*)&PsT[wid][ml][32 + (quad << 3)];

    // ---- PV: O^T += V^T @ P^T^T ----
#pragma unroll
    for (int dt = 0; dt < 4; ++dt) {
      bf16x8 vf0 = *(const bf16x8*)&Vs[dt * 16 + ml][quad << 3];
      bf16x8 vf1 = *(const bf16x8*)&Vs[dt * 16 + ml][32 + (quad << 3)];
      oacc[dt] = __builtin_amdgcn_mfma_f32_16x16x32_bf16(vf0, pf0, oacc[dt], 0, 0, 0);
      oacc[dt] = __builtin_amdgcn_mfma_f32_16x16x32_bf16(vf1, pf1, oacc[dt], 0, 0, 0);
    }
  }

  // ---- epilogue: lane q = q0+wid*16+ml; d = dt*16+quad*4+r ----
  const float inv = 1.f / l_run;
  const int qrow = q0 + wid * 16 + ml;
#pragma unroll
  for (int dt = 0; dt < 4; ++dt)
#pragma unroll
    for (int r = 0; r < 4; ++r)
      O[qkbase + (size_t)qrow * DMODEL + dt * 16 + (quad << 2) + r] =
          f2bfu(oacc[dt][r] * inv);
}

// ---------------------------------------------------------------------------
// out = LayerNorm(X + Y [+ Y2]) * w + b; dtype flags (1 = bf16); Y2 nullable
// ---------------------------------------------------------------------------
__global__ __launch_bounds__(256) void add_ln_kernel(
    const void* __restrict__ X, const void* __restrict__ Y,
    const void* __restrict__ Y2,
    const float* __restrict__ w, const float* __restrict__ bvec,
    void* __restrict__ out, int xbf, int ybf, int obf)
{
  __shared__ float buf[DMODEL];
  __shared__ float rbuf[8];
  const int tid  = threadIdx.x;
  const int lane = tid & 63, wv = tid >> 6;
  const size_t base = (size_t)blockIdx.x * DMODEL;

  float s = 0.f, s2 = 0.f;
#pragma unroll
  for (int j = tid; j < DMODEL; j += 256) {
    float xv = xbf ? bfu2f(((const unsigned short*)X)[base + j])
                   : ((const float*)X)[base + j];
    float yv = ybf ? bfu2f(((const unsigned short*)Y)[base + j])
                   : ((const float*)Y)[base + j];
    float v = xv + yv;
    if (Y2) v += ybf ? bfu2f(((const unsigned short*)Y2)[base + j])
                     : ((const float*)Y2)[base + j];
    buf[j] = v; s += v; s2 += v * v;
  }
#pragma unroll
  for (int o = 32; o; o >>= 1) { s += __shfl_xor(s, o); s2 += __shfl_xor(s2, o); }
  if (lane == 0) { rbuf[wv] = s; rbuf[4 + wv] = s2; }
  __syncthreads();
  const float S  = rbuf[0] + rbuf[1] + rbuf[2] + rbuf[3];
  const float S2 = rbuf[4] + rbuf[5] + rbuf[6] + rbuf[7];
  const float mean = S * (1.f / (float)DMODEL);
  const float var  = S2 * (1.f / (float)DMODEL) - mean * mean;
  const float rstd = rsqrtf(var + 1e-5f);
#pragma unroll
  for (int j = tid; j < DMODEL; j += 256) {
    float v = (buf[j] - mean) * rstd * w[j] + bvec[j];
    if (obf) ((unsigned short*)out)[base + j] = f2bfu(v);
    else     ((float*)out)[base + j] = v;
  }
}

// ---------------------------------------------------------------------------
extern "C" void kernel_launch(void* const* d_in, const int* in_sizes, int n_in,
                              void* d_out, int out_size, void* d_ws, size_t ws_size,
                              hipStream_t stream) {
  const float* src  = (const float*)d_in[0];
  const float* Wq   = (const float*)d_in[1];
  const float* bq   = (const float*)d_in[2];
  const float* Wk   = (const float*)d_in[3];
  const float* bk   = (const float*)d_in[4];
  const float* Wv   = (const float*)d_in[5];
  const float* bv   = (const float*)d_in[6];
  const float* Wo   = (const float*)d_in[7];
  const float* bo   = (const float*)d_in[8];
  const float* ln1w = (const float*)d_in[9];
  const float* ln1b = (const float*)d_in[10];
  const float* W1   = (const float*)d_in[11];
  const float* b1   = (const float*)d_in[12];
  const float* W2   = (const float*)d_in[13];
  const float* b2   = (const float*)d_in[14];
  const float* ln2w = (const float*)d_in[15];
  const float* ln2b = (const float*)d_in[16];
  (void)ws_size; (void)in_sizes; (void)n_in; (void)out_size;

  unsigned short* p = (unsigned short*)d_ws;
  const size_t SEG = (size_t)MROWS * DMODEL;
  unsigned short* srcb = p; p += SEG;
  unsigned short* qb   = p; p += SEG;
  unsigned short* kb_  = p; p += SEG;
  unsigned short* vbT  = p; p += SEG;          // [b,h,64,2048]; later y2 partial 0
  unsigned short* ctx  = p; p += SEG;          // later y2 partial 1
  unsigned short* ff   = p; p += (size_t)MROWS * DFF_K;
  unsigned short* wqt  = p; p += (size_t)DMODEL * DMODEL;
  unsigned short* wkt  = p; p += (size_t)DMODEL * DMODEL;
  unsigned short* wvt  = p; p += (size_t)DMODEL * DMODEL;
  unsigned short* wot  = p; p += (size_t)DMODEL * DMODEL;
  unsigned short* w1t  = p; p += (size_t)DMODEL * DFF_K;
  unsigned short* w2t  = p; p += (size_t)DMODEL * DFF_K;
  unsigned short* ao  = qb;    // dead after attention
  unsigned short* x1  = kb_;   // live through LN2
  unsigned short* y2p = vbT;   // W2 split-K partials: vbT (z0) + ctx (z1), contiguous

  dim3 blk(256);

  // 0: conversions
  convert_kernel<<<dim3(SEG / 1024), blk, 0, stream>>>(src, srcb, (int)(SEG / 4));
  transpose_conv4_kernel<<<dim3(12, 12, 4), blk, 0, stream>>>(
      Wq, Wk, Wv, Wo, wqt, wkt, wvt, wot);
  transpose_conv_kernel<<<dim3(12, 48), blk, 0, stream>>>(W1, w1t, DMODEL, DFF_K, 0);
  transpose_conv_kernel<<<dim3(48, 12), blk, 0, stream>>>(W2, w2t, DFF_K, DMODEL, 0);

  // 1: fused QKV projections (row-block fastest; V written transposed)
  dim3 gqkv(MROWS / 128, DMODEL / 64, 3);      // 32 x 12 x 3
  qkv_gemm_kernel<<<gqkv, blk, 0, stream>>>(srcb, wqt, wkt, wvt, bq, bk, bv,
                                            qb, kb_, vbT);

  // 2: MFMA flash attention (S^T form) -> ctx;  grid (h, b, q-tile)
  dim3 ga(NHEAD, 2, S_LEN / 64);
  flash_attn_mfma<<<ga, blk, 0, stream>>>(qb, kb_, vbT, ctx);

  // 3: attn_out = ctx @ Wo + bo
  dim3 gWo(MROWS / 128, DMODEL / 64, 1);       // 32 x 12
  mfma_gemm_kernel<64><<<gWo, blk, 0, stream>>>(ctx, wot, bo, ao,
                                                DMODEL, DMODEL, 0, DMODEL, 0);

  // 4: x1 = LN(srcb + attn_out)
  add_ln_kernel<<<dim3(MROWS), blk, 0, stream>>>(srcb, ao, nullptr,
                                                 ln1w, ln1b, x1, 1, 1, 1);

  // 5: ff = relu(x1 @ W1 + b1)
  dim3 gF1(MROWS / 128, DFF_K / 128, 1);       // 32 x 24
  mfma_gemm_kernel<128><<<gF1, blk, 0, stream>>>(x1, w1t, b1, ff,
                                                 DMODEL, DFF_K, 1, DMODEL, 0);

  // 6: y2 partials = ff @ W2 + b2, split-K=2 (z=0 adds bias)
  dim3 gW2(MROWS / 128, DMODEL / 64, 2);       // 32 x 12 x 2
  mfma_gemm_kernel<64><<<gW2, blk, 0, stream>>>(ff, w2t, b2, y2p,
                                                DFF_K, DMODEL, 0, DFF_K / 2, SEG);

  // 7: out = LN(x1 + y2p0 + y2p1)
  add_ln_kernel<<<dim3(MROWS), blk, 0, stream>>>(x1, vbT, ctx,
                                                 ln2w, ln2b, (float*)d_out, 1, 1, 0);
}